// Round 6
// baseline (616.000 us; speedup 1.0000x reference)
//
#include <hip/hip_runtime.h>
#include <hip/hip_cooperative_groups.h>

namespace cg = cooperative_groups;

#define NE 8
#define NH 1024
#define NI 1024
#define NGU 2048
#define MTOK 2048
#define TSLOT 4096

#define MAXT64 80     // slow path: 64-row tiles
#define MAXT128 40    // fast path: 128-row tiles
#define NBLK 768      // cooperative grid: 3 blocks/CU x 256 CU

typedef short s16x8 __attribute__((ext_vector_type(8)));
typedef float f32x4 __attribute__((ext_vector_type(4)));
typedef unsigned short u16;

// ---- ws layout (bytes) ----
#define WS_SEG      0
#define WS_DESC64   64
#define WS_DESC128  384
#define WS_SLOT     1024          // 4096 ints -> 17408
#define WS_POS      17408         // 4096 ints -> 33792
#define WS_INTER    33792         // bf16 [4096][1024] -> +8388608 = 8422400
#define WS_AREG     8422400UL     // A bf16 [2048][1024] unsorted (4.19MB) -> 12616704
#define WS_WREG     12616704UL    // WT_gu bf16 33.55MB -> 46171136
#define WS_WTD      46171136UL    // WT_d bf16 16.78MB -> 62948352
#define WS_NEED_FAST  46171136UL
#define WS_NEED_PIGGY 62948352UL

__device__ inline u16 f2bf(float f) {
    unsigned u = __builtin_bit_cast(unsigned, f);
    u += 0x7fffu + ((u >> 16) & 1u);
    return (u16)(u >> 16);
}

__device__ inline void lds_dma16(const u16* g, u16* l) {
    __builtin_amdgcn_global_load_lds(
        (const __attribute__((address_space(1))) unsigned int*)g,
        (__attribute__((address_space(3))) unsigned int*)l, 16, 0, 0);
}

// swizzled LDS byte offset: row-stride 128B (64 bf16), 16B chunks XORed by row&7
__device__ inline int lds_off(int row, int blk) {
    return (row << 7) | (((blk ^ (row & 7)) & 7) << 4);
}

#define PIPE_FENCE asm volatile("" ::: "memory")
#define WAIT_VM6   asm volatile("s_waitcnt vmcnt(6)" ::: "memory")
#define WAIT_VM0   asm volatile("s_waitcnt vmcnt(0)" ::: "memory")

// ---- shared transpose tile: W[K][N] fp32 (one 64x64 tile) -> WT[N][K] bf16 ----
__device__ inline void tr_tile(const float* __restrict__ in, u16* __restrict__ outw,
                               int K, int N, int n0, int k0, int tid, u16 (*T)[66]) {
#pragma unroll
    for (int p = 0; p < 2; ++p) {
        int kr = p * 32 + (tid >> 4) * 2;      // even k row
        int nc = (tid & 15) * 4;
        const float* r0 = in + (size_t)(k0 + kr) * N + n0 + nc;
        float4 v0 = *(const float4*)r0;
        float4 v1 = *(const float4*)(r0 + N);
#pragma unroll
        for (int i = 0; i < 4; ++i) {
            unsigned lo = f2bf(((const float*)&v0)[i]);
            unsigned hi = f2bf(((const float*)&v1)[i]);
            *(unsigned*)&T[nc + i][kr] = lo | (hi << 16);
        }
    }
    __syncthreads();
#pragma unroll
    for (int p = 0; p < 2; ++p) {
        int idx = p * 256 + tid;
        int nr = idx >> 3, kc = (idx & 7) * 8;
        unsigned q0 = *(const unsigned*)&T[nr][kc + 0];
        unsigned q1 = *(const unsigned*)&T[nr][kc + 2];
        unsigned q2 = *(const unsigned*)&T[nr][kc + 4];
        unsigned q3 = *(const unsigned*)&T[nr][kc + 6];
        uint4 vv = {q0, q1, q2, q3};
        *(uint4*)(outw + (size_t)(n0 + nr) * K + k0 + kc) = vv;
    }
}

// ---- expert-sort + tile descriptors (one block) ----
__device__ inline void build_body(const int* __restrict__ ridx, int* __restrict__ seg,
                                  int* __restrict__ d64, int* __restrict__ d128,
                                  int* __restrict__ slot_of, int* __restrict__ pos_of,
                                  int* cnt, int* cur, int tid) {
    if (tid < NE) cnt[tid] = 0;
    __syncthreads();
    for (int s = tid; s < TSLOT; s += 256) atomicAdd(&cnt[ridx[s] & 7], 1);
    __syncthreads();
    if (tid == 0) {
        int a = 0;
        for (int e = 0; e < NE; ++e) { seg[e] = a; cur[e] = a; a += cnt[e]; }
        seg[NE] = a;
        int nt = 0;
        for (int e = 0; e < NE; ++e)
            for (int m0 = 0; m0 < cnt[e]; m0 += 64) d64[nt++] = (e << 16) | (m0 / 64);
        for (; nt < MAXT64; ++nt) d64[nt] = -1;
        nt = 0;
        for (int e = 0; e < NE; ++e)
            for (int m0 = 0; m0 < cnt[e]; m0 += 128) d128[nt++] = (e << 16) | (m0 / 128);
        for (; nt < MAXT128; ++nt) d128[nt] = -1;
    }
    __syncthreads();
    for (int s = tid; s < TSLOT; s += 256) {
        int e = ridx[s] & 7;
        int p = atomicAdd(&cur[e], 1);
        slot_of[p] = s;
        pos_of[s] = p;
    }
}

// ---- shared GEMM pipeline: 128x64 tile, dbuf, counted vmcnt ----
__device__ __forceinline__ void gemm_pipe(const u16* const ap[4], const u16* const bp[2],
                                          char* SM, int tid, int kbeg, int nsteps,
                                          f32x4 (&acc)[4][2]) {
    u16* As0 = (u16*)SM;
    u16* As1 = (u16*)(SM + 16384);
    u16* Bs0 = (u16*)(SM + 32768);
    u16* Bs1 = (u16*)(SM + 40960);
    int lane = tid & 63, w = tid >> 6;
    int ml = lane & 15, kq = lane >> 4;
    int wm = w >> 1, wn = w & 1;

    auto stage = [&](u16* AS, u16* BS, int kb) {
#pragma unroll
        for (int c = 0; c < 4; ++c) lds_dma16(ap[c] + kb, AS + c * 2048 + w * 512);
#pragma unroll
        for (int c = 0; c < 2; ++c) lds_dma16(bp[c] + kb, BS + c * 2048 + w * 512);
    };
    auto compute = [&](const u16* AS, const u16* BS) {
#pragma unroll
        for (int kk = 0; kk < 64; kk += 32) {
            s16x8 af[4], bf[2];
#pragma unroll
            for (int i = 0; i < 4; ++i)
                af[i] = *(const s16x8*)((const char*)AS + lds_off(wm * 64 + i * 16 + ml, (kk >> 3) + kq));
#pragma unroll
            for (int i = 0; i < 2; ++i)
                bf[i] = *(const s16x8*)((const char*)BS + lds_off(wn * 32 + i * 16 + ml, (kk >> 3) + kq));
#pragma unroll
            for (int mi = 0; mi < 4; ++mi)
#pragma unroll
                for (int ni = 0; ni < 2; ++ni)
                    acc[mi][ni] = __builtin_amdgcn_mfma_f32_16x16x32_bf16(
                        af[mi], bf[ni], acc[mi][ni], 0, 0, 0);
        }
    };

    stage(As0, Bs0, kbeg);
    for (int t = 0; t < nsteps; t += 2) {
        stage(As1, Bs1, kbeg + ((t + 1) << 6));
        WAIT_VM6;
        __builtin_amdgcn_s_barrier();
        PIPE_FENCE;
        __builtin_amdgcn_s_setprio(1);
        compute(As0, Bs0);
        __builtin_amdgcn_s_setprio(0);
        PIPE_FENCE;
        __builtin_amdgcn_s_barrier();
        if (t < nsteps - 2) {
            stage(As0, Bs0, kbeg + ((t + 2) << 6));
            WAIT_VM6;
        } else {
            WAIT_VM0;
        }
        __builtin_amdgcn_s_barrier();
        PIPE_FENCE;
        __builtin_amdgcn_s_setprio(1);
        compute(As1, Bs1);
        __builtin_amdgcn_s_setprio(0);
        PIPE_FENCE;
        __builtin_amdgcn_s_barrier();
    }
}

// ---- gate_up tile job: GEMM + swiglu epilogue ----
__device__ __forceinline__ void job_gateup(
        int d, int y, const u16* __restrict__ A, const u16* __restrict__ wt,
        const float* __restrict__ bias, const int* __restrict__ seg,
        const int* __restrict__ slot_of, u16* __restrict__ inter,
        char* SM, int tid) {
    int e = d >> 16, mt = d & 0xffff;
    int seg0 = seg[e], Te = seg[e + 1] - seg0, m0 = mt * 128;
    int lane = tid & 63, w = tid >> 6;
    int ml = lane & 15, kq = lane >> 4;
    int wm = w >> 1, wn = w & 1;
    int n0 = y * 64;
    int dr = lane >> 3, db = (lane & 7) ^ dr;
    const u16* wte = wt + (size_t)e * NGU * NH;

    const u16* ap[4];
#pragma unroll
    for (int c = 0; c < 4; ++c) {
        int gr = seg0 + m0 + c * 32 + w * 8 + dr;
        if (gr > TSLOT - 1) gr = TSLOT - 1;
        int tok = slot_of[gr] >> 1;
        ap[c] = A + (size_t)tok * NH + db * 8;
    }
    const u16* bp[2];
#pragma unroll
    for (int c = 0; c < 2; ++c)
        bp[c] = wte + (size_t)(n0 + c * 32 + w * 8 + dr) * NH + db * 8;

    f32x4 zero = {0.f, 0.f, 0.f, 0.f};
    f32x4 acc[4][2];
#pragma unroll
    for (int i = 0; i < 4; ++i) { acc[i][0] = zero; acc[i][1] = zero; }

    gemm_pipe(ap, bp, SM, tid, 0, 16, acc);

#pragma unroll
    for (int ni = 0; ni < 2; ++ni) {
        int n = n0 + wn * 32 + ni * 16 + ml;
        float bv = bias[e * NGU + n];
#pragma unroll
        for (int mi = 0; mi < 4; ++mi) {
#pragma unroll
            for (int r = 0; r < 4; ++r) {
                float v = acc[mi][ni][r] + bv;
                float pr = __shfl_xor(v, 1, 64);
                float g = (lane & 1) ? pr : v;
                float u = (lane & 1) ? v : pr;
                g = fminf(g, 7.0f);
                u = fminf(fmaxf(u, -7.0f), 7.0f);
                float glu = g / (1.0f + __expf(-1.702f * g));
                float yv = (u + 1.0f) * glu;
                int mloc = wm * 64 + mi * 16 + kq * 4 + r;
                if (!(lane & 1) && (m0 + mloc) < Te)
                    inter[(size_t)(seg0 + m0 + mloc) * NI + (n >> 1)] = f2bf(yv);
            }
        }
    }
}

// ---- down tile job: split-K GEMM + weighted atomic scatter epilogue ----
__device__ __forceinline__ void job_down(
        int d, int y, int kz, const u16* __restrict__ inter, const u16* __restrict__ wt,
        const float* __restrict__ bias, const float* __restrict__ rw,
        const int* __restrict__ seg, const int* __restrict__ slot_of,
        float* __restrict__ out, char* SM, int tid) {
    int e = d >> 16, mt = d & 0xffff;
    int seg0 = seg[e], Te = seg[e + 1] - seg0, m0 = mt * 128;
    int* tokS = (int*)(SM + 49152);
    float* wgtS = (float*)(SM + 49664);

    if (tid < 128) {
        int m = m0 + tid;
        if (m < Te) {
            int token = slot_of[seg0 + m] >> 1;
            tokS[tid] = token;
            wgtS[tid] = rw[token * NE + e];
        } else {
            tokS[tid] = 0;
            wgtS[tid] = 0.0f;
        }
    }

    int lane = tid & 63, w = tid >> 6;
    int ml = lane & 15, kq = lane >> 4;
    int wm = w >> 1, wn = w & 1;
    int n0 = y * 64;
    int dr = lane >> 3, db = (lane & 7) ^ dr;
    const u16* wte = wt + (size_t)e * NH * NI;

    const u16* ap[4];
#pragma unroll
    for (int c = 0; c < 4; ++c) {
        int gr = seg0 + m0 + c * 32 + w * 8 + dr;
        if (gr > TSLOT - 1) gr = TSLOT - 1;
        ap[c] = inter + (size_t)gr * NI + db * 8;
    }
    const u16* bp[2];
#pragma unroll
    for (int c = 0; c < 2; ++c)
        bp[c] = wte + (size_t)(n0 + c * 32 + w * 8 + dr) * NI + db * 8;

    f32x4 zero = {0.f, 0.f, 0.f, 0.f};
    f32x4 acc[4][2];
#pragma unroll
    for (int i = 0; i < 4; ++i) { acc[i][0] = zero; acc[i][1] = zero; }

    gemm_pipe(ap, bp, SM, tid, kz * (NI / 2), 8, acc);

    float bv[2];
#pragma unroll
    for (int ni = 0; ni < 2; ++ni)
        bv[ni] = kz ? 0.0f : bias[e * NH + n0 + wn * 32 + ni * 16 + ml];

#pragma unroll
    for (int mi = 0; mi < 4; ++mi) {
#pragma unroll
        for (int r = 0; r < 4; ++r) {
            int mloc = wm * 64 + mi * 16 + kq * 4 + r;
            if ((m0 + mloc) < Te) {
                int token = tokS[mloc];
                float wgt = wgtS[mloc];
#pragma unroll
                for (int ni = 0; ni < 2; ++ni) {
                    int n = n0 + wn * 32 + ni * 16 + ml;
                    atomicAdd(&out[(size_t)token * NH + n], (acc[mi][ni][r] + bv[ni]) * wgt);
                }
            }
        }
    }
}

// ================= cooperative megakernel: 3 phases, 2 grid syncs =================
__global__ __launch_bounds__(256, 3) void k_mega(
        const float* __restrict__ x, const int* __restrict__ ri,
        const float* __restrict__ rw,
        const float* __restrict__ wgu, const float* __restrict__ bgu,
        const float* __restrict__ wd, const float* __restrict__ bd,
        int* __restrict__ seg, int* __restrict__ d64, int* __restrict__ d128,
        int* __restrict__ slot_of, int* __restrict__ pos_of,
        u16* __restrict__ A, u16* __restrict__ wtgu, u16* __restrict__ wtd,
        u16* __restrict__ inter, float* __restrict__ out) {
    __shared__ __align__(16) char SM[50176];
    int tid = threadIdx.x;
    int bid = blockIdx.x;
    cg::grid_group grid = cg::this_grid();

    // ---- phase 0: build(1) + convert/zero(2048) + tr_gu(4096) + tr_d(2048) ----
    const int P0 = 1 + MTOK + 4096 + 2048;
    for (int j = bid; j < P0; j += NBLK) {
        __syncthreads();
        if (j == 0) {
            build_body(ri, seg, d64, d128, slot_of, pos_of,
                       (int*)SM, (int*)SM + NE, tid);
        } else if (j <= MTOK) {
            int t = j - 1;
            float4 v = ((const float4*)(x + (size_t)t * NH))[tid];
            ushort4 o;
            o.x = f2bf(v.x); o.y = f2bf(v.y); o.z = f2bf(v.z); o.w = f2bf(v.w);
            ((ushort4*)(A + (size_t)t * NH))[tid] = o;
            float4 z = {0.f, 0.f, 0.f, 0.f};
            ((float4*)(out + (size_t)t * NH))[tid] = z;
        } else if (j <= MTOK + 4096) {
            int id = j - (MTOK + 1);
            int e = id >> 9, rem = id & 511;
            int kblk = rem >> 5, nblk = rem & 31;
            tr_tile(wgu + (size_t)e * NH * NGU, wtgu + (size_t)e * NGU * NH,
                    NH, NGU, nblk * 64, kblk * 64, tid, (u16(*)[66])SM);
        } else {
            int id = j - (MTOK + 4097);
            int e = id >> 8, rem = id & 255;
            int kblk = rem >> 4, nblk = rem & 15;
            tr_tile(wd + (size_t)e * NI * NH, wtd + (size_t)e * NH * NI,
                    NI, NH, nblk * 64, kblk * 64, tid, (u16(*)[66])SM);
        }
    }
    __threadfence();
    grid.sync();

    // ---- phase 1: gate_up GEMM, 1280 jobs ----
    for (int j = bid; j < MAXT128 * 32; j += NBLK) {
        __syncthreads();
        int xt = j % MAXT128, y = j / MAXT128;
        int d = d128[xt];
        if (d < 0) continue;
        job_gateup(d, y, A, wtgu, bgu, seg, slot_of, inter, SM, tid);
    }
    __threadfence();
    grid.sync();

    // ---- phase 2: down GEMM split-Kx2, 1280 jobs ----
    for (int j = bid; j < MAXT128 * 32; j += NBLK) {
        __syncthreads();
        int xt = j % MAXT128;
        int rest = j / MAXT128;
        int y = rest & 15, kz = rest >> 4;
        int d = d128[xt];
        if (d < 0) continue;
        job_down(d, y, kz, inter, wtd, bd, rw, seg, slot_of, out, SM, tid);
    }
}

// ================= fallback standalone kernels (R5-proven path) =================
__global__ __launch_bounds__(256) void k_tr(const float* __restrict__ W,
                                            u16* __restrict__ WT, int K, int N) {
    __shared__ u16 T[64][66];
    tr_tile(W + (size_t)blockIdx.z * K * N, WT + (size_t)blockIdx.z * N * K,
            K, N, blockIdx.x * 64, blockIdx.y * 64, threadIdx.x, T);
}

__global__ __launch_bounds__(256) void k_prep(
        const float* __restrict__ x, const int* __restrict__ ridx,
        const float* __restrict__ wgu,
        int* __restrict__ seg, int* __restrict__ d64, int* __restrict__ d128,
        int* __restrict__ slot_of, int* __restrict__ pos_of,
        u16* __restrict__ A, u16* __restrict__ wt_gu, float* __restrict__ out) {
    __shared__ int cnt[NE];
    __shared__ int cur[NE];
    __shared__ u16 T[64][66];
    int b = blockIdx.x;
    int tid = threadIdx.x;
    if (b == 0) {
        build_body(ridx, seg, d64, d128, slot_of, pos_of, cnt, cur, tid);
    } else if (b <= MTOK) {
        int t = b - 1;
        float4 v = ((const float4*)(x + (size_t)t * NH))[tid];
        ushort4 o;
        o.x = f2bf(v.x); o.y = f2bf(v.y); o.z = f2bf(v.z); o.w = f2bf(v.w);
        ((ushort4*)(A + (size_t)t * NH))[tid] = o;
        float4 z = {0.f, 0.f, 0.f, 0.f};
        ((float4*)(out + (size_t)t * NH))[tid] = z;
    } else {
        int id = b - (MTOK + 1);
        int e = id >> 9, rem = id & 511;
        int kblk = rem >> 5, nblk = rem & 31;
        tr_tile(wgu + (size_t)e * NH * NGU, wt_gu + (size_t)e * NGU * NH,
                NH, NGU, nblk * 64, kblk * 64, tid, T);
    }
}

__global__ __launch_bounds__(256) void k_gateup_f(
        const u16* __restrict__ A, const u16* __restrict__ wt,
        const float* __restrict__ bias,
        const int* __restrict__ seg, const int* __restrict__ desc,
        const int* __restrict__ slot_of, u16* __restrict__ inter,
        const float* __restrict__ wd, u16* __restrict__ wtd) {
    __shared__ __align__(16) char SM[50176];
    int tid = threadIdx.x;
    if (blockIdx.x >= MAXT128) {
        int id = (blockIdx.x - MAXT128) * 32 + blockIdx.y;
        int e = id >> 8, rem = id & 255;
        int kblk = rem >> 4, nblk = rem & 15;
        tr_tile(wd + (size_t)e * NI * NH, wtd + (size_t)e * NH * NI,
                NI, NH, nblk * 64, kblk * 64, tid, (u16(*)[66])SM);
        return;
    }
    int d = desc[blockIdx.x];
    if (d < 0) return;
    job_gateup(d, blockIdx.y, A, wt, bias, seg, slot_of, inter, SM, tid);
}

__global__ __launch_bounds__(256) void k_down_f(
        const u16* __restrict__ inter, const u16* __restrict__ wt,
        const float* __restrict__ bias, const float* __restrict__ rw,
        const int* __restrict__ seg, const int* __restrict__ desc,
        const int* __restrict__ slot_of, float* __restrict__ out) {
    __shared__ __align__(16) char SM[50176];
    int d = desc[blockIdx.x];
    if (d < 0) return;
    job_down(d, blockIdx.y, blockIdx.z, inter, wt, bias, rw, seg, slot_of, out,
             SM, threadIdx.x);
}

// ---------------- slow-path kernels (proven) ----------------
__global__ void k_build(const int* __restrict__ ridx, int* __restrict__ seg,
                        int* __restrict__ d64, int* __restrict__ d128,
                        int* __restrict__ slot_of, int* __restrict__ pos_of) {
    __shared__ int cnt[NE];
    __shared__ int cur[NE];
    build_body(ridx, seg, d64, d128, slot_of, pos_of, cnt, cur, threadIdx.x);
}

__global__ __launch_bounds__(256) void k_gateup_s(
        const float* __restrict__ x, const float* __restrict__ w,
        const float* __restrict__ bias,
        const int* __restrict__ seg, const int* __restrict__ desc,
        const int* __restrict__ slot_of, u16* __restrict__ inter) {
    int d = desc[blockIdx.x];
    if (d < 0) return;
    int e = d >> 16, mt = d & 0xffff;
    int seg0 = seg[e], Te = seg[e + 1] - seg0, m0 = mt * 64;
    __shared__ u16 As[64 * 40];
    __shared__ int tok[64];
    int tid = threadIdx.x;
    if (tid < 64) {
        int m = m0 + tid;
        tok[tid] = (m < Te) ? (slot_of[seg0 + m] >> 1) : -1;
    }
    __syncthreads();
    int lane = tid & 63, wave = tid >> 6;
    int arow = tid >> 2, acol = (tid & 3) * 8;
    int ta = tok[arow];
    int kq = lane >> 4, ml = lane & 15;
    int nb = blockIdx.y * 128 + wave * 32;
    const float* wp = w + (size_t)e * NH * NGU;
    f32x4 zero = {0.f, 0.f, 0.f, 0.f};
    f32x4 acc[4][2];
#pragma unroll
    for (int i = 0; i < 4; ++i) { acc[i][0] = zero; acc[i][1] = zero; }
    for (int kb = 0; kb < NH; kb += 32) {
        float4 a0 = {0, 0, 0, 0}, a1 = {0, 0, 0, 0};
        if (ta >= 0) {
            const float* xp = x + (size_t)ta * NH + kb + acol;
            a0 = *(const float4*)xp; a1 = *(const float4*)(xp + 4);
        }
        s16x8 av;
        av[0] = (short)f2bf(a0.x); av[1] = (short)f2bf(a0.y);
        av[2] = (short)f2bf(a0.z); av[3] = (short)f2bf(a0.w);
        av[4] = (short)f2bf(a1.x); av[5] = (short)f2bf(a1.y);
        av[6] = (short)f2bf(a1.z); av[7] = (short)f2bf(a1.w);
        __syncthreads();
        *(s16x8*)&As[arow * 40 + acol] = av;
        __syncthreads();
        s16x8 afr[4];
#pragma unroll
        for (int msi = 0; msi < 4; ++msi)
            afr[msi] = *(const s16x8*)&As[(msi * 16 + ml) * 40 + kq * 8];
        s16x8 bfr[2];
#pragma unroll
        for (int s = 0; s < 2; ++s) {
            const float* bp = wp + (size_t)(kb + kq * 8) * NGU + nb + s * 16 + ml;
#pragma unroll
            for (int j = 0; j < 8; ++j) bfr[s][j] = (short)f2bf(bp[(size_t)j * NGU]);
        }
#pragma unroll
        for (int msi = 0; msi < 4; ++msi)
#pragma unroll
            for (int s = 0; s < 2; ++s)
                acc[msi][s] = __builtin_amdgcn_mfma_f32_16x16x32_bf16(
                    afr[msi], bfr[s], acc[msi][s], 0, 0, 0);
    }
#pragma unroll
    for (int s = 0; s < 2; ++s) {
        int n = nb + s * 16 + ml;
        float bv = bias[e * NGU + n];
#pragma unroll
        for (int msi = 0; msi < 4; ++msi) {
#pragma unroll
            for (int r = 0; r < 4; ++r) {
                float v = acc[msi][s][r] + bv;
                float pr = __shfl_xor(v, 1, 64);
                float g = (lane & 1) ? pr : v;
                float u = (lane & 1) ? v : pr;
                g = fminf(g, 7.0f);
                u = fminf(fmaxf(u, -7.0f), 7.0f);
                float glu = g / (1.0f + __expf(-1.702f * g));
                float y = (u + 1.0f) * glu;
                int mrow = m0 + msi * 16 + kq * 4 + r;
                if (!(lane & 1) && mrow < Te)
                    inter[(size_t)(seg0 + mrow) * NI + (n >> 1)] = f2bf(y);
            }
        }
    }
}

__global__ __launch_bounds__(256) void k_down_s(
        const u16* __restrict__ inter, const float* __restrict__ w,
        const float* __restrict__ bias, const float* __restrict__ rw,
        const int* __restrict__ seg, const int* __restrict__ desc,
        const int* __restrict__ slot_of, float* __restrict__ out) {
    int d = desc[blockIdx.x];
    if (d < 0) return;
    int e = d >> 16, mt = d & 0xffff;
    int seg0 = seg[e], Te = seg[e + 1] - seg0, m0 = mt * 64;
    __shared__ u16 As[64 * 40];
    int tid = threadIdx.x;
    int lane = tid & 63, wave = tid >> 6;
    int arow = tid >> 2, acol = (tid & 3) * 8;
    bool avalid = (m0 + arow) < Te;
    int kq = lane >> 4, ml = lane & 15;
    int nb = blockIdx.y * 128 + wave * 32;
    const float* wp = w + (size_t)e * NI * NH;
    f32x4 zero = {0.f, 0.f, 0.f, 0.f};
    f32x4 acc[4][2];
#pragma unroll
    for (int i = 0; i < 4; ++i) { acc[i][0] = zero; acc[i][1] = zero; }
    for (int kb = 0; kb < NI; kb += 32) {
        s16x8 av = {0, 0, 0, 0, 0, 0, 0, 0};
        if (avalid) av = *(const s16x8*)(inter + (size_t)(seg0 + m0 + arow) * NI + kb + acol);
        __syncthreads();
        *(s16x8*)&As[arow * 40 + acol] = av;
        __syncthreads();
        s16x8 afr[4];
#pragma unroll
        for (int msi = 0; msi < 4; ++msi)
            afr[msi] = *(const s16x8*)&As[(msi * 16 + ml) * 40 + kq * 8];
        s16x8 bfr[2];
#pragma unroll
        for (int s = 0; s < 2; ++s) {
            const float* bp = wp + (size_t)(kb + kq * 8) * NH + nb + s * 16 + ml;
#pragma unroll
            for (int j = 0; j < 8; ++j) bfr[s][j] = (short)f2bf(bp[(size_t)j * NH]);
        }
#pragma unroll
        for (int msi = 0; msi < 4; ++msi)
#pragma unroll
            for (int s = 0; s < 2; ++s)
                acc[msi][s] = __builtin_amdgcn_mfma_f32_16x16x32_bf16(
                    afr[msi], bfr[s], acc[msi][s], 0, 0, 0);
    }
    float bv[2];
    bv[0] = bias[e * NH + nb + ml];
    bv[1] = bias[e * NH + nb + 16 + ml];
#pragma unroll
    for (int msi = 0; msi < 4; ++msi) {
#pragma unroll
        for (int r = 0; r < 4; ++r) {
            int mrow = m0 + msi * 16 + kq * 4 + r;
            if (mrow < Te) {
                int slot = slot_of[seg0 + mrow];
                int token = slot >> 1;
                float wgt = rw[token * NE + e];
#pragma unroll
                for (int s = 0; s < 2; ++s) {
                    int n = nb + s * 16 + ml;
                    atomicAdd(&out[(size_t)token * NH + n], (acc[msi][s][r] + bv[s]) * wgt);
                }
            }
        }
    }
}

extern "C" void kernel_launch(void* const* d_in, const int* in_sizes, int n_in,
                              void* d_out, int out_size, void* d_ws, size_t ws_size,
                              hipStream_t stream) {
    const float* x   = (const float*)d_in[0];
    const int*   ri  = (const int*)d_in[1];
    const float* rw  = (const float*)d_in[2];
    const float* wgu = (const float*)d_in[3];
    const float* bgu = (const float*)d_in[4];
    const float* wd  = (const float*)d_in[5];
    const float* bd  = (const float*)d_in[6];
    float* out = (float*)d_out;

    char* ws = (char*)d_ws;
    int* seg     = (int*)(ws + WS_SEG);
    int* d64     = (int*)(ws + WS_DESC64);
    int* d128    = (int*)(ws + WS_DESC128);
    int* slot_of = (int*)(ws + WS_SLOT);
    int* pos_of  = (int*)(ws + WS_POS);
    u16* inter   = (u16*)(ws + WS_INTER);

    static int g_coop = -1;
    if (g_coop < 0) {
        int dev = 0;
        (void)hipGetDevice(&dev);
        int v = 0;
        if (hipDeviceGetAttribute(&v, hipDeviceAttributeCooperativeLaunch, dev) != hipSuccess)
            v = 0;
        g_coop = v;
    }

    if (ws_size >= WS_NEED_PIGGY) {
        u16* aReg = (u16*)(ws + WS_AREG);
        u16* wReg = (u16*)(ws + WS_WREG);     // WT_gu
        u16* wtd  = (u16*)(ws + WS_WTD);      // WT_d (disjoint)

        if (g_coop) {
            void* args[] = {(void*)&x, (void*)&ri, (void*)&rw, (void*)&wgu, (void*)&bgu,
                            (void*)&wd, (void*)&bd, (void*)&seg, (void*)&d64, (void*)&d128,
                            (void*)&slot_of, (void*)&pos_of, (void*)&aReg, (void*)&wReg,
                            (void*)&wtd, (void*)&inter, (void*)&out};
            hipError_t err = hipLaunchCooperativeKernel(
                (const void*)k_mega, dim3(NBLK), dim3(256), args, 0, stream);
            if (err == hipSuccess) return;
            (void)hipGetLastError();   // clear; fall through to 3-launch path
        }

        hipLaunchKernelGGL(k_prep, dim3(1 + MTOK + 4096), dim3(256), 0, stream,
                           x, ri, wgu, seg, d64, d128, slot_of, pos_of, aReg, wReg, out);
        hipLaunchKernelGGL(k_gateup_f, dim3(MAXT128 + 64, NGU / 64), dim3(256), 0, stream,
                           aReg, wReg, bgu, seg, d128, slot_of, inter, wd, wtd);
        hipLaunchKernelGGL(k_down_f, dim3(MAXT128, NH / 64, 2), dim3(256), 0, stream,
                           inter, wtd, bd, rw, seg, d128, slot_of, out);
    } else if (ws_size >= WS_NEED_FAST) {
        u16* aReg = (u16*)(ws + WS_AREG);
        u16* wReg = (u16*)(ws + WS_WREG);
        hipLaunchKernelGGL(k_prep, dim3(1 + MTOK + 4096), dim3(256), 0, stream,
                           x, ri, wgu, seg, d64, d128, slot_of, pos_of, aReg, wReg, out);
        hipLaunchKernelGGL(k_gateup_f, dim3(MAXT128, NGU / 64), dim3(256), 0, stream,
                           aReg, wReg, bgu, seg, d128, slot_of, inter, wd, wReg);
        hipLaunchKernelGGL(k_tr, dim3(NH / 64, NI / 64, NE), dim3(256), 0, stream,
                           wd, wReg, NI, NH);
        hipLaunchKernelGGL(k_down_f, dim3(MAXT128, NH / 64, 2), dim3(256), 0, stream,
                           inter, wReg, bd, rw, seg, d128, slot_of, out);
    } else {
        hipLaunchKernelGGL(k_build, dim3(1), dim3(256), 0, stream, ri, seg, d64, d128,
                           slot_of, pos_of);
        hipMemsetAsync(out, 0, (size_t)MTOK * NH * sizeof(float), stream);
        hipLaunchKernelGGL(k_gateup_s, dim3(MAXT64, NGU / 128), dim3(256), 0, stream,
                           x, wgu, bgu, seg, d64, slot_of, inter);
        hipLaunchKernelGGL(k_down_s, dim3(MAXT64, NH / 128), dim3(256), 0, stream,
                           inter, wd, bd, rw, seg, d64, slot_of, out);
    }
}

// Round 7
// 225.394 us; speedup vs baseline: 2.7330x; 2.7330x over previous
//
#include <hip/hip_runtime.h>

#define NE 8
#define NH 1024
#define NI 1024
#define NGU 2048
#define MTOK 2048
#define TSLOT 4096

#define MAXT64 80     // slow path: 64-row tiles
#define MAXT128 40    // fast path: 128-row tiles

typedef short s16x8 __attribute__((ext_vector_type(8)));
typedef float f32x4 __attribute__((ext_vector_type(4)));
typedef unsigned short u16;

// ---- ws layout (bytes) ----
#define WS_SEG      0
#define WS_DESC64   64
#define WS_DESC128  384
#define WS_SLOT     1024          // 4096 ints -> 17408
#define WS_POS      17408         // 4096 ints -> 33792
#define WS_INTER    33792         // bf16 [4096][1024] -> +8388608 = 8422400
#define WS_AREG     8422400UL     // A bf16 [2048][1024] unsorted (4.19MB) -> 12616704
#define WS_WREG     12616704UL    // WT_gu bf16 33.55MB -> 46171136
#define WS_WTD      46171136UL    // WT_d bf16 16.78MB -> 62948352
#define WS_NEED_FAST  46171136UL
#define WS_NEED_PIGGY 62948352UL

__device__ inline u16 f2bf(float f) {
    unsigned u = __builtin_bit_cast(unsigned, f);
    u += 0x7fffu + ((u >> 16) & 1u);
    return (u16)(u >> 16);
}

__device__ inline void lds_dma16(const u16* g, u16* l) {
    __builtin_amdgcn_global_load_lds(
        (const __attribute__((address_space(1))) unsigned int*)g,
        (__attribute__((address_space(3))) unsigned int*)l, 16, 0, 0);
}

// swizzled LDS byte offset: row-stride 128B (64 bf16), 16B chunks XORed by row&7
__device__ inline int lds_off(int row, int blk) {
    return (row << 7) | (((blk ^ (row & 7)) & 7) << 4);
}

#define PIPE_FENCE asm volatile("" ::: "memory")
#define WAIT_VM6   asm volatile("s_waitcnt vmcnt(6)" ::: "memory")
#define WAIT_VM0   asm volatile("s_waitcnt vmcnt(0)" ::: "memory")

// ---- shared transpose tile: W[K][N] fp32 (one 64x64 tile) -> WT[N][K] bf16 ----
__device__ inline void tr_tile(const float* __restrict__ in, u16* __restrict__ outw,
                               int K, int N, int n0, int k0, int tid, u16 (*T)[66]) {
#pragma unroll
    for (int p = 0; p < 2; ++p) {
        int kr = p * 32 + (tid >> 4) * 2;      // even k row
        int nc = (tid & 15) * 4;
        const float* r0 = in + (size_t)(k0 + kr) * N + n0 + nc;
        float4 v0 = *(const float4*)r0;
        float4 v1 = *(const float4*)(r0 + N);
#pragma unroll
        for (int i = 0; i < 4; ++i) {
            unsigned lo = f2bf(((const float*)&v0)[i]);
            unsigned hi = f2bf(((const float*)&v1)[i]);
            *(unsigned*)&T[nc + i][kr] = lo | (hi << 16);
        }
    }
    __syncthreads();
#pragma unroll
    for (int p = 0; p < 2; ++p) {
        int idx = p * 256 + tid;
        int nr = idx >> 3, kc = (idx & 7) * 8;
        unsigned q0 = *(const unsigned*)&T[nr][kc + 0];
        unsigned q1 = *(const unsigned*)&T[nr][kc + 2];
        unsigned q2 = *(const unsigned*)&T[nr][kc + 4];
        unsigned q3 = *(const unsigned*)&T[nr][kc + 6];
        uint4 vv = {q0, q1, q2, q3};
        *(uint4*)(outw + (size_t)(n0 + nr) * K + k0 + kc) = vv;
    }
}

// ---- expert-sort + tile descriptors (one block) ----
__device__ inline void build_body(const int* __restrict__ ridx, int* __restrict__ seg,
                                  int* __restrict__ d64, int* __restrict__ d128,
                                  int* __restrict__ slot_of, int* __restrict__ pos_of,
                                  int* cnt, int* cur, int tid) {
    if (tid < NE) cnt[tid] = 0;
    __syncthreads();
    for (int s = tid; s < TSLOT; s += 256) atomicAdd(&cnt[ridx[s] & 7], 1);
    __syncthreads();
    if (tid == 0) {
        int a = 0;
        for (int e = 0; e < NE; ++e) { seg[e] = a; cur[e] = a; a += cnt[e]; }
        seg[NE] = a;
        int nt = 0;
        for (int e = 0; e < NE; ++e)
            for (int m0 = 0; m0 < cnt[e]; m0 += 64) d64[nt++] = (e << 16) | (m0 / 64);
        for (; nt < MAXT64; ++nt) d64[nt] = -1;
        nt = 0;
        for (int e = 0; e < NE; ++e)
            for (int m0 = 0; m0 < cnt[e]; m0 += 128) d128[nt++] = (e << 16) | (m0 / 128);
        for (; nt < MAXT128; ++nt) d128[nt] = -1;
    }
    __syncthreads();
    for (int s = tid; s < TSLOT; s += 256) {
        int e = ridx[s] & 7;
        int p = atomicAdd(&cur[e], 1);
        slot_of[p] = s;
        pos_of[s] = p;
    }
}

// ---- shared GEMM pipeline: 128x64 tile, dbuf, counted vmcnt ----
__device__ __forceinline__ void gemm_pipe(const u16* const ap[4], const u16* const bp[2],
                                          char* SM, int tid, int kbeg, int nsteps,
                                          f32x4 (&acc)[4][2]) {
    u16* As0 = (u16*)SM;
    u16* As1 = (u16*)(SM + 16384);
    u16* Bs0 = (u16*)(SM + 32768);
    u16* Bs1 = (u16*)(SM + 40960);
    int lane = tid & 63, w = tid >> 6;
    int ml = lane & 15, kq = lane >> 4;
    int wm = w >> 1, wn = w & 1;

    auto stage = [&](u16* AS, u16* BS, int kb) {
#pragma unroll
        for (int c = 0; c < 4; ++c) lds_dma16(ap[c] + kb, AS + c * 2048 + w * 512);
#pragma unroll
        for (int c = 0; c < 2; ++c) lds_dma16(bp[c] + kb, BS + c * 2048 + w * 512);
    };
    auto compute = [&](const u16* AS, const u16* BS) {
#pragma unroll
        for (int kk = 0; kk < 64; kk += 32) {
            s16x8 af[4], bf[2];
#pragma unroll
            for (int i = 0; i < 4; ++i)
                af[i] = *(const s16x8*)((const char*)AS + lds_off(wm * 64 + i * 16 + ml, (kk >> 3) + kq));
#pragma unroll
            for (int i = 0; i < 2; ++i)
                bf[i] = *(const s16x8*)((const char*)BS + lds_off(wn * 32 + i * 16 + ml, (kk >> 3) + kq));
#pragma unroll
            for (int mi = 0; mi < 4; ++mi)
#pragma unroll
                for (int ni = 0; ni < 2; ++ni)
                    acc[mi][ni] = __builtin_amdgcn_mfma_f32_16x16x32_bf16(
                        af[mi], bf[ni], acc[mi][ni], 0, 0, 0);
        }
    };

    stage(As0, Bs0, kbeg);
    for (int t = 0; t < nsteps; t += 2) {
        stage(As1, Bs1, kbeg + ((t + 1) << 6));
        WAIT_VM6;
        __builtin_amdgcn_s_barrier();
        PIPE_FENCE;
        __builtin_amdgcn_s_setprio(1);
        compute(As0, Bs0);
        __builtin_amdgcn_s_setprio(0);
        PIPE_FENCE;
        __builtin_amdgcn_s_barrier();
        if (t < nsteps - 2) {
            stage(As0, Bs0, kbeg + ((t + 2) << 6));
            WAIT_VM6;
        } else {
            WAIT_VM0;
        }
        __builtin_amdgcn_s_barrier();
        PIPE_FENCE;
        __builtin_amdgcn_s_setprio(1);
        compute(As1, Bs1);
        __builtin_amdgcn_s_setprio(0);
        PIPE_FENCE;
        __builtin_amdgcn_s_barrier();
    }
}

// ---- gate_up tile job: GEMM + swiglu epilogue ----
__device__ __forceinline__ void job_gateup(
        int d, int y, const u16* __restrict__ A, const u16* __restrict__ wt,
        const float* __restrict__ bias, const int* __restrict__ seg,
        const int* __restrict__ slot_of, u16* __restrict__ inter,
        char* SM, int tid) {
    int e = d >> 16, mt = d & 0xffff;
    int seg0 = seg[e], Te = seg[e + 1] - seg0, m0 = mt * 128;
    int lane = tid & 63, w = tid >> 6;
    int ml = lane & 15, kq = lane >> 4;
    int wm = w >> 1, wn = w & 1;
    int n0 = y * 64;
    int dr = lane >> 3, db = (lane & 7) ^ dr;
    const u16* wte = wt + (size_t)e * NGU * NH;

    const u16* ap[4];
#pragma unroll
    for (int c = 0; c < 4; ++c) {
        int gr = seg0 + m0 + c * 32 + w * 8 + dr;
        if (gr > TSLOT - 1) gr = TSLOT - 1;
        int tok = slot_of[gr] >> 1;
        ap[c] = A + (size_t)tok * NH + db * 8;
    }
    const u16* bp[2];
#pragma unroll
    for (int c = 0; c < 2; ++c)
        bp[c] = wte + (size_t)(n0 + c * 32 + w * 8 + dr) * NH + db * 8;

    f32x4 zero = {0.f, 0.f, 0.f, 0.f};
    f32x4 acc[4][2];
#pragma unroll
    for (int i = 0; i < 4; ++i) { acc[i][0] = zero; acc[i][1] = zero; }

    gemm_pipe(ap, bp, SM, tid, 0, 16, acc);

#pragma unroll
    for (int ni = 0; ni < 2; ++ni) {
        int n = n0 + wn * 32 + ni * 16 + ml;
        float bv = bias[e * NGU + n];
#pragma unroll
        for (int mi = 0; mi < 4; ++mi) {
#pragma unroll
            for (int r = 0; r < 4; ++r) {
                float v = acc[mi][ni][r] + bv;
                float pr = __shfl_xor(v, 1, 64);
                float g = (lane & 1) ? pr : v;
                float u = (lane & 1) ? v : pr;
                g = fminf(g, 7.0f);
                u = fminf(fmaxf(u, -7.0f), 7.0f);
                float glu = g / (1.0f + __expf(-1.702f * g));
                float yv = (u + 1.0f) * glu;
                int mloc = wm * 64 + mi * 16 + kq * 4 + r;
                if (!(lane & 1) && (m0 + mloc) < Te)
                    inter[(size_t)(seg0 + m0 + mloc) * NI + (n >> 1)] = f2bf(yv);
            }
        }
    }
}

// ---- down tile job: split-K GEMM + weighted atomic scatter epilogue ----
__device__ __forceinline__ void job_down(
        int d, int y, int kz, const u16* __restrict__ inter, const u16* __restrict__ wt,
        const float* __restrict__ bias, const float* __restrict__ rw,
        const int* __restrict__ seg, const int* __restrict__ slot_of,
        float* __restrict__ out, char* SM, int tid) {
    int e = d >> 16, mt = d & 0xffff;
    int seg0 = seg[e], Te = seg[e + 1] - seg0, m0 = mt * 128;
    int* tokS = (int*)(SM + 49152);
    float* wgtS = (float*)(SM + 49664);

    if (tid < 128) {
        int m = m0 + tid;
        if (m < Te) {
            int token = slot_of[seg0 + m] >> 1;
            tokS[tid] = token;
            wgtS[tid] = rw[token * NE + e];
        } else {
            tokS[tid] = 0;
            wgtS[tid] = 0.0f;
        }
    }

    int lane = tid & 63, w = tid >> 6;
    int ml = lane & 15, kq = lane >> 4;
    int wm = w >> 1, wn = w & 1;
    int n0 = y * 64;
    int dr = lane >> 3, db = (lane & 7) ^ dr;
    const u16* wte = wt + (size_t)e * NH * NI;

    const u16* ap[4];
#pragma unroll
    for (int c = 0; c < 4; ++c) {
        int gr = seg0 + m0 + c * 32 + w * 8 + dr;
        if (gr > TSLOT - 1) gr = TSLOT - 1;
        ap[c] = inter + (size_t)gr * NI + db * 8;
    }
    const u16* bp[2];
#pragma unroll
    for (int c = 0; c < 2; ++c)
        bp[c] = wte + (size_t)(n0 + c * 32 + w * 8 + dr) * NI + db * 8;

    f32x4 zero = {0.f, 0.f, 0.f, 0.f};
    f32x4 acc[4][2];
#pragma unroll
    for (int i = 0; i < 4; ++i) { acc[i][0] = zero; acc[i][1] = zero; }

    gemm_pipe(ap, bp, SM, tid, kz * (NI / 2), 8, acc);

    float bv[2];
#pragma unroll
    for (int ni = 0; ni < 2; ++ni)
        bv[ni] = kz ? 0.0f : bias[e * NH + n0 + wn * 32 + ni * 16 + ml];

#pragma unroll
    for (int mi = 0; mi < 4; ++mi) {
#pragma unroll
        for (int r = 0; r < 4; ++r) {
            int mloc = wm * 64 + mi * 16 + kq * 4 + r;
            if ((m0 + mloc) < Te) {
                int token = tokS[mloc];
                float wgt = wgtS[mloc];
#pragma unroll
                for (int ni = 0; ni < 2; ++ni) {
                    int n = n0 + wn * 32 + ni * 16 + ml;
                    atomicAdd(&out[(size_t)token * NH + n], (acc[mi][ni][r] + bv[ni]) * wgt);
                }
            }
        }
    }
}

// ---------------- fused prep: build(1) + convert/zero(2048) + tr_gu(4096) + tr_d(2048) ----------------
__global__ __launch_bounds__(256) void k_prep(
        const float* __restrict__ x, const int* __restrict__ ridx,
        const float* __restrict__ wgu, const float* __restrict__ wd,
        int* __restrict__ seg, int* __restrict__ d64, int* __restrict__ d128,
        int* __restrict__ slot_of, int* __restrict__ pos_of,
        u16* __restrict__ A, u16* __restrict__ wt_gu, u16* __restrict__ wt_d,
        float* __restrict__ out) {
    __shared__ int cnt[NE];
    __shared__ int cur[NE];
    __shared__ u16 T[64][66];
    int b = blockIdx.x;
    int tid = threadIdx.x;
    if (b == 0) {
        build_body(ridx, seg, d64, d128, slot_of, pos_of, cnt, cur, tid);
    } else if (b <= MTOK) {
        int t = b - 1;
        float4 v = ((const float4*)(x + (size_t)t * NH))[tid];
        ushort4 o;
        o.x = f2bf(v.x); o.y = f2bf(v.y); o.z = f2bf(v.z); o.w = f2bf(v.w);
        ((ushort4*)(A + (size_t)t * NH))[tid] = o;
        float4 z = {0.f, 0.f, 0.f, 0.f};
        ((float4*)(out + (size_t)t * NH))[tid] = z;
    } else if (b <= MTOK + 4096) {
        int id = b - (MTOK + 1);                 // 0..4095
        int e = id >> 9, rem = id & 511;
        int kblk = rem >> 5, nblk = rem & 31;    // K=NH: 16 kblks, N=NGU: 32 nblks
        tr_tile(wgu + (size_t)e * NH * NGU, wt_gu + (size_t)e * NGU * NH,
                NH, NGU, nblk * 64, kblk * 64, tid, T);
    } else {
        int id = b - (MTOK + 4097);              // 0..2047
        int e = id >> 8, rem = id & 255;
        int kblk = rem >> 4, nblk = rem & 15;    // K=NI:16, N=NH:16
        tr_tile(wd + (size_t)e * NI * NH, wt_d + (size_t)e * NH * NI,
                NI, NH, nblk * 64, kblk * 64, tid, T);
    }
}

// ---------------- fast gate_up: pure GEMM launch ----------------
__global__ __launch_bounds__(256) void k_gateup_f(
        const u16* __restrict__ A, const u16* __restrict__ wt,
        const float* __restrict__ bias,
        const int* __restrict__ seg, const int* __restrict__ desc,
        const int* __restrict__ slot_of, u16* __restrict__ inter) {
    __shared__ __align__(16) char SM[50176];
    int d = desc[blockIdx.x];
    if (d < 0) return;
    job_gateup(d, blockIdx.y, A, wt, bias, seg, slot_of, inter, SM, threadIdx.x);
}

// ---------------- fast down: split-Kx2 GEMM + fused weighted atomic scatter ----------------
__global__ __launch_bounds__(256) void k_down_f(
        const u16* __restrict__ inter, const u16* __restrict__ wt,
        const float* __restrict__ bias, const float* __restrict__ rw,
        const int* __restrict__ seg, const int* __restrict__ desc,
        const int* __restrict__ slot_of, float* __restrict__ out) {
    __shared__ __align__(16) char SM[50176];
    int d = desc[blockIdx.x];
    if (d < 0) return;
    job_down(d, blockIdx.y, blockIdx.z, inter, wt, bias, rw, seg, slot_of, out,
             SM, threadIdx.x);
}

// ---------------- fallback standalone transpose ----------------
__global__ __launch_bounds__(256) void k_tr(const float* __restrict__ W,
                                            u16* __restrict__ WT, int K, int N) {
    __shared__ u16 T[64][66];
    tr_tile(W + (size_t)blockIdx.z * K * N, WT + (size_t)blockIdx.z * N * K,
            K, N, blockIdx.x * 64, blockIdx.y * 64, threadIdx.x, T);
}

// ---------------- slow-path kernels (proven) ----------------
__global__ void k_build(const int* __restrict__ ridx, int* __restrict__ seg,
                        int* __restrict__ d64, int* __restrict__ d128,
                        int* __restrict__ slot_of, int* __restrict__ pos_of) {
    __shared__ int cnt[NE];
    __shared__ int cur[NE];
    build_body(ridx, seg, d64, d128, slot_of, pos_of, cnt, cur, threadIdx.x);
}

__global__ __launch_bounds__(256) void k_gateup_s(
        const float* __restrict__ x, const float* __restrict__ w,
        const float* __restrict__ bias,
        const int* __restrict__ seg, const int* __restrict__ desc,
        const int* __restrict__ slot_of, u16* __restrict__ inter) {
    int d = desc[blockIdx.x];
    if (d < 0) return;
    int e = d >> 16, mt = d & 0xffff;
    int seg0 = seg[e], Te = seg[e + 1] - seg0, m0 = mt * 64;
    __shared__ u16 As[64 * 40];
    __shared__ int tok[64];
    int tid = threadIdx.x;
    if (tid < 64) {
        int m = m0 + tid;
        tok[tid] = (m < Te) ? (slot_of[seg0 + m] >> 1) : -1;
    }
    __syncthreads();
    int lane = tid & 63, wave = tid >> 6;
    int arow = tid >> 2, acol = (tid & 3) * 8;
    int ta = tok[arow];
    int kq = lane >> 4, ml = lane & 15;
    int nb = blockIdx.y * 128 + wave * 32;
    const float* wp = w + (size_t)e * NH * NGU;
    f32x4 zero = {0.f, 0.f, 0.f, 0.f};
    f32x4 acc[4][2];
#pragma unroll
    for (int i = 0; i < 4; ++i) { acc[i][0] = zero; acc[i][1] = zero; }
    for (int kb = 0; kb < NH; kb += 32) {
        float4 a0 = {0, 0, 0, 0}, a1 = {0, 0, 0, 0};
        if (ta >= 0) {
            const float* xp = x + (size_t)ta * NH + kb + acol;
            a0 = *(const float4*)xp; a1 = *(const float4*)(xp + 4);
        }
        s16x8 av;
        av[0] = (short)f2bf(a0.x); av[1] = (short)f2bf(a0.y);
        av[2] = (short)f2bf(a0.z); av[3] = (short)f2bf(a0.w);
        av[4] = (short)f2bf(a1.x); av[5] = (short)f2bf(a1.y);
        av[6] = (short)f2bf(a1.z); av[7] = (short)f2bf(a1.w);
        __syncthreads();
        *(s16x8*)&As[arow * 40 + acol] = av;
        __syncthreads();
        s16x8 afr[4];
#pragma unroll
        for (int msi = 0; msi < 4; ++msi)
            afr[msi] = *(const s16x8*)&As[(msi * 16 + ml) * 40 + kq * 8];
        s16x8 bfr[2];
#pragma unroll
        for (int s = 0; s < 2; ++s) {
            const float* bp = wp + (size_t)(kb + kq * 8) * NGU + nb + s * 16 + ml;
#pragma unroll
            for (int j = 0; j < 8; ++j) bfr[s][j] = (short)f2bf(bp[(size_t)j * NGU]);
        }
#pragma unroll
        for (int msi = 0; msi < 4; ++msi)
#pragma unroll
            for (int s = 0; s < 2; ++s)
                acc[msi][s] = __builtin_amdgcn_mfma_f32_16x16x32_bf16(
                    afr[msi], bfr[s], acc[msi][s], 0, 0, 0);
    }
#pragma unroll
    for (int s = 0; s < 2; ++s) {
        int n = nb + s * 16 + ml;
        float bv = bias[e * NGU + n];
#pragma unroll
        for (int msi = 0; msi < 4; ++msi) {
#pragma unroll
            for (int r = 0; r < 4; ++r) {
                float v = acc[msi][s][r] + bv;
                float pr = __shfl_xor(v, 1, 64);
                float g = (lane & 1) ? pr : v;
                float u = (lane & 1) ? v : pr;
                g = fminf(g, 7.0f);
                u = fminf(fmaxf(u, -7.0f), 7.0f);
                float glu = g / (1.0f + __expf(-1.702f * g));
                float y = (u + 1.0f) * glu;
                int mrow = m0 + msi * 16 + kq * 4 + r;
                if (!(lane & 1) && mrow < Te)
                    inter[(size_t)(seg0 + mrow) * NI + (n >> 1)] = f2bf(y);
            }
        }
    }
}

__global__ __launch_bounds__(256) void k_down_s(
        const u16* __restrict__ inter, const float* __restrict__ w,
        const float* __restrict__ bias, const float* __restrict__ rw,
        const int* __restrict__ seg, const int* __restrict__ desc,
        const int* __restrict__ slot_of, float* __restrict__ out) {
    int d = desc[blockIdx.x];
    if (d < 0) return;
    int e = d >> 16, mt = d & 0xffff;
    int seg0 = seg[e], Te = seg[e + 1] - seg0, m0 = mt * 64;
    __shared__ u16 As[64 * 40];
    int tid = threadIdx.x;
    int lane = tid & 63, wave = tid >> 6;
    int arow = tid >> 2, acol = (tid & 3) * 8;
    bool avalid = (m0 + arow) < Te;
    int kq = lane >> 4, ml = lane & 15;
    int nb = blockIdx.y * 128 + wave * 32;
    const float* wp = w + (size_t)e * NI * NH;
    f32x4 zero = {0.f, 0.f, 0.f, 0.f};
    f32x4 acc[4][2];
#pragma unroll
    for (int i = 0; i < 4; ++i) { acc[i][0] = zero; acc[i][1] = zero; }
    for (int kb = 0; kb < NI; kb += 32) {
        s16x8 av = {0, 0, 0, 0, 0, 0, 0, 0};
        if (avalid) av = *(const s16x8*)(inter + (size_t)(seg0 + m0 + arow) * NI + kb + acol);
        __syncthreads();
        *(s16x8*)&As[arow * 40 + acol] = av;
        __syncthreads();
        s16x8 afr[4];
#pragma unroll
        for (int msi = 0; msi < 4; ++msi)
            afr[msi] = *(const s16x8*)&As[(msi * 16 + ml) * 40 + kq * 8];
        s16x8 bfr[2];
#pragma unroll
        for (int s = 0; s < 2; ++s) {
            const float* bp = wp + (size_t)(kb + kq * 8) * NH + nb + s * 16 + ml;
#pragma unroll
            for (int j = 0; j < 8; ++j) bfr[s][j] = (short)f2bf(bp[(size_t)j * NH]);
        }
#pragma unroll
        for (int msi = 0; msi < 4; ++msi)
#pragma unroll
            for (int s = 0; s < 2; ++s)
                acc[msi][s] = __builtin_amdgcn_mfma_f32_16x16x32_bf16(
                    afr[msi], bfr[s], acc[msi][s], 0, 0, 0);
    }
    float bv[2];
    bv[0] = bias[e * NH + nb + ml];
    bv[1] = bias[e * NH + nb + 16 + ml];
#pragma unroll
    for (int msi = 0; msi < 4; ++msi) {
#pragma unroll
        for (int r = 0; r < 4; ++r) {
            int mrow = m0 + msi * 16 + kq * 4 + r;
            if (mrow < Te) {
                int slot = slot_of[seg0 + mrow];
                int token = slot >> 1;
                float wgt = rw[token * NE + e];
#pragma unroll
                for (int s = 0; s < 2; ++s) {
                    int n = nb + s * 16 + ml;
                    atomicAdd(&out[(size_t)token * NH + n], (acc[msi][s][r] + bv[s]) * wgt);
                }
            }
        }
    }
}

extern "C" void kernel_launch(void* const* d_in, const int* in_sizes, int n_in,
                              void* d_out, int out_size, void* d_ws, size_t ws_size,
                              hipStream_t stream) {
    const float* x   = (const float*)d_in[0];
    const int*   ri  = (const int*)d_in[1];
    const float* rw  = (const float*)d_in[2];
    const float* wgu = (const float*)d_in[3];
    const float* bgu = (const float*)d_in[4];
    const float* wd  = (const float*)d_in[5];
    const float* bd  = (const float*)d_in[6];
    float* out = (float*)d_out;

    char* ws = (char*)d_ws;
    int* seg     = (int*)(ws + WS_SEG);
    int* d64     = (int*)(ws + WS_DESC64);
    int* d128    = (int*)(ws + WS_DESC128);
    int* slot_of = (int*)(ws + WS_SLOT);
    int* pos_of  = (int*)(ws + WS_POS);
    u16* inter   = (u16*)(ws + WS_INTER);

    if (ws_size >= WS_NEED_PIGGY) {
        u16* aReg = (u16*)(ws + WS_AREG);
        u16* wReg = (u16*)(ws + WS_WREG);     // WT_gu
        u16* wtd  = (u16*)(ws + WS_WTD);      // WT_d (disjoint)
        // launch 1: build + x->bf16 + out zero + BOTH weight transposes
        hipLaunchKernelGGL(k_prep, dim3(1 + MTOK + 4096 + 2048), dim3(256), 0, stream,
                           x, ri, wgu, wd, seg, d64, d128, slot_of, pos_of,
                           aReg, wReg, wtd, out);
        // launch 2: pure gate_up GEMM (640 blocks, proven 43.6us config)
        hipLaunchKernelGGL(k_gateup_f, dim3(MAXT128, NGU / 64), dim3(256), 0, stream,
                           aReg, wReg, bgu, seg, d128, slot_of, inter);
        // launch 3: down GEMM split-Kx2 (1280 blocks, proven config) + atomic scatter
        hipLaunchKernelGGL(k_down_f, dim3(MAXT128, NH / 64, 2), dim3(256), 0, stream,
                           inter, wtd, bd, rw, seg, d128, slot_of, out);
    } else if (ws_size >= WS_NEED_FAST) {
        u16* aReg = (u16*)(ws + WS_AREG);
        u16* wReg = (u16*)(ws + WS_WREG);
        hipLaunchKernelGGL(k_prep, dim3(1 + MTOK + 4096), dim3(256), 0, stream,
                           x, ri, wgu, wd, seg, d64, d128, slot_of, pos_of,
                           aReg, wReg, wReg /*unused tr_d range*/, out);
        hipLaunchKernelGGL(k_gateup_f, dim3(MAXT128, NGU / 64), dim3(256), 0, stream,
                           aReg, wReg, bgu, seg, d128, slot_of, inter);
        hipLaunchKernelGGL(k_tr, dim3(NH / 64, NI / 64, NE), dim3(256), 0, stream,
                           wd, wReg, NI, NH);
        hipLaunchKernelGGL(k_down_f, dim3(MAXT128, NH / 64, 2), dim3(256), 0, stream,
                           inter, wReg, bd, rw, seg, d128, slot_of, out);
    } else {
        hipLaunchKernelGGL(k_build, dim3(1), dim3(256), 0, stream, ri, seg, d64, d128,
                           slot_of, pos_of);
        hipMemsetAsync(out, 0, (size_t)MTOK * NH * sizeof(float), stream);
        hipLaunchKernelGGL(k_gateup_s, dim3(MAXT64, NGU / 128), dim3(256), 0, stream,
                           x, wgu, bgu, seg, d64, slot_of, inter);
        hipLaunchKernelGGL(k_down_s, dim3(MAXT64, NH / 128), dim3(256), 0, stream,
                           inter, wd, bd, rw, seg, d64, slot_of, out);
    }
}

// Round 8
// 219.234 us; speedup vs baseline: 2.8098x; 1.0281x over previous
//
#include <hip/hip_runtime.h>

#define NE 8
#define NH 1024
#define NI 1024
#define NGU 2048
#define MTOK 2048
#define TSLOT 4096

#define MAXT64 80     // slow path: 64-row tiles
#define MAXT128 40    // fast path: 128-row tiles

typedef short s16x8 __attribute__((ext_vector_type(8)));
typedef float f32x4 __attribute__((ext_vector_type(4)));
typedef unsigned short u16;

// ---- ws layout (bytes) ----
#define WS_SEG      0
#define WS_DESC64   64
#define WS_DESC128  384
#define WS_SLOT     1024          // 4096 ints -> 17408
#define WS_POS      17408         // 4096 ints -> 33792
#define WS_INTER    33792         // bf16 [4096][1024] -> +8388608 = 8422400
#define WS_AREG     8422400UL     // A bf16 [2048][1024] unsorted (4.19MB) -> 12616704
#define WS_WREG     12616704UL    // WT_gu bf16 33.55MB -> 46171136
#define WS_WTD      46171136UL    // WT_d bf16 16.78MB -> 62948352
#define WS_NEED_FAST  46171136UL
#define WS_NEED_PIGGY 62948352UL

__device__ inline u16 f2bf(float f) {
    unsigned u = __builtin_bit_cast(unsigned, f);
    u += 0x7fffu + ((u >> 16) & 1u);
    return (u16)(u >> 16);
}

__device__ inline void lds_dma16(const u16* g, u16* l) {
    __builtin_amdgcn_global_load_lds(
        (const __attribute__((address_space(1))) unsigned int*)g,
        (__attribute__((address_space(3))) unsigned int*)l, 16, 0, 0);
}

// swizzled LDS byte offset: row-stride 128B (64 bf16), 16B chunks XORed by row&7
__device__ inline int lds_off(int row, int blk) {
    return (row << 7) | (((blk ^ (row & 7)) & 7) << 4);
}

#define PIPE_FENCE asm volatile("" ::: "memory")
#define WAIT_VM6   asm volatile("s_waitcnt vmcnt(6)" ::: "memory")
#define WAIT_VM0   asm volatile("s_waitcnt vmcnt(0)" ::: "memory")

// ---- transpose tile into TILED layout: WT[e][k/64][n][64] ----
// output tile (k0,n0) = 8KB fully contiguous block at ((k0/64)*N + n0)*64
__device__ inline void tr_tile(const float* __restrict__ in, u16* __restrict__ outw,
                               int K, int N, int n0, int k0, int tid, u16 (*T)[66]) {
#pragma unroll
    for (int p = 0; p < 2; ++p) {
        int kr = p * 32 + (tid >> 4) * 2;      // even k row
        int nc = (tid & 15) * 4;
        const float* r0 = in + (size_t)(k0 + kr) * N + n0 + nc;
        float4 v0 = *(const float4*)r0;
        float4 v1 = *(const float4*)(r0 + N);
#pragma unroll
        for (int i = 0; i < 4; ++i) {
            unsigned lo = f2bf(((const float*)&v0)[i]);
            unsigned hi = f2bf(((const float*)&v1)[i]);
            *(unsigned*)&T[nc + i][kr] = lo | (hi << 16);
        }
    }
    __syncthreads();
#pragma unroll
    for (int p = 0; p < 2; ++p) {
        int idx = p * 256 + tid;
        int nr = idx >> 3, kc = (idx & 7) * 8;
        unsigned q0 = *(const unsigned*)&T[nr][kc + 0];
        unsigned q1 = *(const unsigned*)&T[nr][kc + 2];
        unsigned q2 = *(const unsigned*)&T[nr][kc + 4];
        unsigned q3 = *(const unsigned*)&T[nr][kc + 6];
        uint4 vv = {q0, q1, q2, q3};
        *(uint4*)(outw + ((size_t)(k0 >> 6) * N + n0 + nr) * 64 + kc) = vv;
    }
}

// ---- expert-sort (STABLE counting sort: ascending slot within expert) + descriptors ----
__device__ inline void build_body(const int* __restrict__ ridx, int* __restrict__ seg,
                                  int* __restrict__ d64, int* __restrict__ d128,
                                  int* __restrict__ slot_of, int* __restrict__ pos_of,
                                  int tid) {
    __shared__ int hist[256][NE];
    __shared__ int cnt[NE];
#pragma unroll
    for (int e = 0; e < NE; ++e) hist[tid][e] = 0;
    __syncthreads();
    for (int i = 0; i < 16; ++i) {
        int e = ridx[tid * 16 + i] & 7;
        hist[tid][e]++;
    }
    __syncthreads();
    if (tid < NE) {
        int run = 0;
        for (int c = 0; c < 256; ++c) { int t = hist[c][tid]; hist[c][tid] = run; run += t; }
        cnt[tid] = run;
    }
    __syncthreads();
    if (tid == 0) {
        int a = 0;
        for (int e = 0; e < NE; ++e) { seg[e] = a; a += cnt[e]; }
        seg[NE] = a;
        int nt = 0;
        for (int e = 0; e < NE; ++e)
            for (int m0 = 0; m0 < cnt[e]; m0 += 64) d64[nt++] = (e << 16) | (m0 / 64);
        for (; nt < MAXT64; ++nt) d64[nt] = -1;
        nt = 0;
        for (int e = 0; e < NE; ++e)
            for (int m0 = 0; m0 < cnt[e]; m0 += 128) d128[nt++] = (e << 16) | (m0 / 128);
        for (; nt < MAXT128; ++nt) d128[nt] = -1;
    }
    __syncthreads();
    for (int i = 0; i < 16; ++i) {
        int s = tid * 16 + i;
        int e = ridx[s] & 7;
        int p = seg[e] + hist[tid][e]++;
        slot_of[p] = s;
        pos_of[s] = p;
    }
}

// ---- shared GEMM pipeline: 128x64 tile, dbuf, counted vmcnt; B in tiled layout ----
__device__ __forceinline__ void gemm_pipe(const u16* const ap[4], const u16* const bp[2],
                                          size_t bks, char* SM, int tid, int kbeg,
                                          int nsteps, f32x4 (&acc)[4][2]) {
    u16* As0 = (u16*)SM;
    u16* As1 = (u16*)(SM + 16384);
    u16* Bs0 = (u16*)(SM + 32768);
    u16* Bs1 = (u16*)(SM + 40960);
    int lane = tid & 63, w = tid >> 6;
    int ml = lane & 15, kq = lane >> 4;
    int wm = w >> 1, wn = w & 1;

    auto stage = [&](u16* AS, u16* BS, int kb) {
#pragma unroll
        for (int c = 0; c < 4; ++c) lds_dma16(ap[c] + kb, AS + c * 2048 + w * 512);
        size_t bo = (size_t)(kb >> 6) * bks;
#pragma unroll
        for (int c = 0; c < 2; ++c) lds_dma16(bp[c] + bo, BS + c * 2048 + w * 512);
    };
    auto compute = [&](const u16* AS, const u16* BS) {
#pragma unroll
        for (int kk = 0; kk < 64; kk += 32) {
            s16x8 af[4], bf[2];
#pragma unroll
            for (int i = 0; i < 4; ++i)
                af[i] = *(const s16x8*)((const char*)AS + lds_off(wm * 64 + i * 16 + ml, (kk >> 3) + kq));
#pragma unroll
            for (int i = 0; i < 2; ++i)
                bf[i] = *(const s16x8*)((const char*)BS + lds_off(wn * 32 + i * 16 + ml, (kk >> 3) + kq));
#pragma unroll
            for (int mi = 0; mi < 4; ++mi)
#pragma unroll
                for (int ni = 0; ni < 2; ++ni)
                    acc[mi][ni] = __builtin_amdgcn_mfma_f32_16x16x32_bf16(
                        af[mi], bf[ni], acc[mi][ni], 0, 0, 0);
        }
    };

    stage(As0, Bs0, kbeg);
    for (int t = 0; t < nsteps; t += 2) {
        stage(As1, Bs1, kbeg + ((t + 1) << 6));
        WAIT_VM6;
        __builtin_amdgcn_s_barrier();
        PIPE_FENCE;
        __builtin_amdgcn_s_setprio(1);
        compute(As0, Bs0);
        __builtin_amdgcn_s_setprio(0);
        PIPE_FENCE;
        __builtin_amdgcn_s_barrier();
        if (t < nsteps - 2) {
            stage(As0, Bs0, kbeg + ((t + 2) << 6));
            WAIT_VM6;
        } else {
            WAIT_VM0;
        }
        __builtin_amdgcn_s_barrier();
        PIPE_FENCE;
        __builtin_amdgcn_s_setprio(1);
        compute(As1, Bs1);
        __builtin_amdgcn_s_setprio(0);
        PIPE_FENCE;
        __builtin_amdgcn_s_barrier();
    }
}

// ---- gate_up tile job: GEMM + swiglu epilogue ----
__device__ __forceinline__ void job_gateup(
        int d, int y, const u16* __restrict__ A, const u16* __restrict__ wt,
        const float* __restrict__ bias, const int* __restrict__ seg,
        const int* __restrict__ slot_of, u16* __restrict__ inter,
        char* SM, int tid) {
    int e = d >> 16, mt = d & 0xffff;
    int seg0 = seg[e], Te = seg[e + 1] - seg0, m0 = mt * 128;
    int lane = tid & 63, w = tid >> 6;
    int ml = lane & 15, kq = lane >> 4;
    int wm = w >> 1, wn = w & 1;
    int n0 = y * 64;
    int dr = lane >> 3, db = (lane & 7) ^ dr;
    const u16* wte = wt + (size_t)e * NGU * NH;   // tiled: [NH/64][NGU][64]

    const u16* ap[4];
#pragma unroll
    for (int c = 0; c < 4; ++c) {
        int gr = seg0 + m0 + c * 32 + w * 8 + dr;
        if (gr > TSLOT - 1) gr = TSLOT - 1;
        int tok = slot_of[gr] >> 1;
        ap[c] = A + (size_t)tok * NH + db * 8;
    }
    const u16* bp[2];
#pragma unroll
    for (int c = 0; c < 2; ++c)
        bp[c] = wte + (size_t)(n0 + c * 32 + w * 8 + dr) * 64 + db * 8;

    f32x4 zero = {0.f, 0.f, 0.f, 0.f};
    f32x4 acc[4][2];
#pragma unroll
    for (int i = 0; i < 4; ++i) { acc[i][0] = zero; acc[i][1] = zero; }

    gemm_pipe(ap, bp, (size_t)NGU * 64, SM, tid, 0, 16, acc);

#pragma unroll
    for (int ni = 0; ni < 2; ++ni) {
        int n = n0 + wn * 32 + ni * 16 + ml;
        float bv = bias[e * NGU + n];
#pragma unroll
        for (int mi = 0; mi < 4; ++mi) {
#pragma unroll
            for (int r = 0; r < 4; ++r) {
                float v = acc[mi][ni][r] + bv;
                float pr = __shfl_xor(v, 1, 64);
                float g = (lane & 1) ? pr : v;
                float u = (lane & 1) ? v : pr;
                g = fminf(g, 7.0f);
                u = fminf(fmaxf(u, -7.0f), 7.0f);
                float glu = g / (1.0f + __expf(-1.702f * g));
                float yv = (u + 1.0f) * glu;
                int mloc = wm * 64 + mi * 16 + kq * 4 + r;
                if (!(lane & 1) && (m0 + mloc) < Te)
                    inter[(size_t)(seg0 + m0 + mloc) * NI + (n >> 1)] = f2bf(yv);
            }
        }
    }
}

// ---- down tile job: split-K GEMM + weighted atomic scatter epilogue ----
__device__ __forceinline__ void job_down(
        int d, int y, int kz, const u16* __restrict__ inter, const u16* __restrict__ wt,
        const float* __restrict__ bias, const float* __restrict__ rw,
        const int* __restrict__ seg, const int* __restrict__ slot_of,
        float* __restrict__ out, char* SM, int tid) {
    int e = d >> 16, mt = d & 0xffff;
    int seg0 = seg[e], Te = seg[e + 1] - seg0, m0 = mt * 128;
    int* tokS = (int*)(SM + 49152);
    float* wgtS = (float*)(SM + 49664);

    if (tid < 128) {
        int m = m0 + tid;
        if (m < Te) {
            int token = slot_of[seg0 + m] >> 1;
            tokS[tid] = token;
            wgtS[tid] = rw[token * NE + e];
        } else {
            tokS[tid] = 0;
            wgtS[tid] = 0.0f;
        }
    }

    int lane = tid & 63, w = tid >> 6;
    int ml = lane & 15, kq = lane >> 4;
    int wm = w >> 1, wn = w & 1;
    int n0 = y * 64;
    int dr = lane >> 3, db = (lane & 7) ^ dr;
    const u16* wte = wt + (size_t)e * NH * NI;    // tiled: [NI/64][NH][64]

    const u16* ap[4];
#pragma unroll
    for (int c = 0; c < 4; ++c) {
        int gr = seg0 + m0 + c * 32 + w * 8 + dr;
        if (gr > TSLOT - 1) gr = TSLOT - 1;
        ap[c] = inter + (size_t)gr * NI + db * 8;
    }
    const u16* bp[2];
#pragma unroll
    for (int c = 0; c < 2; ++c)
        bp[c] = wte + (size_t)(n0 + c * 32 + w * 8 + dr) * 64 + db * 8;

    f32x4 zero = {0.f, 0.f, 0.f, 0.f};
    f32x4 acc[4][2];
#pragma unroll
    for (int i = 0; i < 4; ++i) { acc[i][0] = zero; acc[i][1] = zero; }

    gemm_pipe(ap, bp, (size_t)NH * 64, SM, tid, kz * (NI / 2), 8, acc);

    float bv[2];
#pragma unroll
    for (int ni = 0; ni < 2; ++ni)
        bv[ni] = kz ? 0.0f : bias[e * NH + n0 + wn * 32 + ni * 16 + ml];

#pragma unroll
    for (int mi = 0; mi < 4; ++mi) {
#pragma unroll
        for (int r = 0; r < 4; ++r) {
            int mloc = wm * 64 + mi * 16 + kq * 4 + r;
            if ((m0 + mloc) < Te) {
                int token = tokS[mloc];
                float wgt = wgtS[mloc];
#pragma unroll
                for (int ni = 0; ni < 2; ++ni) {
                    int n = n0 + wn * 32 + ni * 16 + ml;
                    atomicAdd(&out[(size_t)token * NH + n], (acc[mi][ni][r] + bv[ni]) * wgt);
                }
            }
        }
    }
}

// ---------------- fused prep: build(1) + convert/zero(2048) + tr_gu(4096) + tr_d(2048) ----------------
__global__ __launch_bounds__(256) void k_prep(
        const float* __restrict__ x, const int* __restrict__ ridx,
        const float* __restrict__ wgu, const float* __restrict__ wd,
        int* __restrict__ seg, int* __restrict__ d64, int* __restrict__ d128,
        int* __restrict__ slot_of, int* __restrict__ pos_of,
        u16* __restrict__ A, u16* __restrict__ wt_gu, u16* __restrict__ wt_d,
        float* __restrict__ out) {
    __shared__ u16 T[64][66];
    int b = blockIdx.x;
    int tid = threadIdx.x;
    if (b == 0) {
        build_body(ridx, seg, d64, d128, slot_of, pos_of, tid);
    } else if (b <= MTOK) {
        int t = b - 1;
        float4 v = ((const float4*)(x + (size_t)t * NH))[tid];
        ushort4 o;
        o.x = f2bf(v.x); o.y = f2bf(v.y); o.z = f2bf(v.z); o.w = f2bf(v.w);
        ((ushort4*)(A + (size_t)t * NH))[tid] = o;
        float4 z = {0.f, 0.f, 0.f, 0.f};
        ((float4*)(out + (size_t)t * NH))[tid] = z;
    } else if (b <= MTOK + 4096) {
        int id = b - (MTOK + 1);                 // 0..4095
        int e = id >> 9, rem = id & 511;
        int kblk = rem >> 5, nblk = rem & 31;    // K=NH: 16 kblks, N=NGU: 32 nblks
        tr_tile(wgu + (size_t)e * NH * NGU, wt_gu + (size_t)e * NGU * NH,
                NH, NGU, nblk * 64, kblk * 64, tid, T);
    } else {
        int id = b - (MTOK + 4097);              // 0..2047
        int e = id >> 8, rem = id & 255;
        int kblk = rem >> 4, nblk = rem & 15;    // K=NI:16, N=NH:16
        tr_tile(wd + (size_t)e * NI * NH, wt_d + (size_t)e * NH * NI,
                NI, NH, nblk * 64, kblk * 64, tid, T);
    }
}

// ---------------- fast gate_up: pure GEMM launch ----------------
__global__ __launch_bounds__(256) void k_gateup_f(
        const u16* __restrict__ A, const u16* __restrict__ wt,
        const float* __restrict__ bias,
        const int* __restrict__ seg, const int* __restrict__ desc,
        const int* __restrict__ slot_of, u16* __restrict__ inter) {
    __shared__ __align__(16) char SM[50176];
    int d = desc[blockIdx.x];
    if (d < 0) return;
    job_gateup(d, blockIdx.y, A, wt, bias, seg, slot_of, inter, SM, threadIdx.x);
}

// ---------------- fast down: split-Kx2 GEMM + fused weighted atomic scatter ----------------
__global__ __launch_bounds__(256) void k_down_f(
        const u16* __restrict__ inter, const u16* __restrict__ wt,
        const float* __restrict__ bias, const float* __restrict__ rw,
        const int* __restrict__ seg, const int* __restrict__ desc,
        const int* __restrict__ slot_of, float* __restrict__ out) {
    __shared__ __align__(16) char SM[50176];
    int d = desc[blockIdx.x];
    if (d < 0) return;
    job_down(d, blockIdx.y, blockIdx.z, inter, wt, bias, rw, seg, slot_of, out,
             SM, threadIdx.x);
}

// ---------------- fallback standalone transpose ----------------
__global__ __launch_bounds__(256) void k_tr(const float* __restrict__ W,
                                            u16* __restrict__ WT, int K, int N) {
    __shared__ u16 T[64][66];
    tr_tile(W + (size_t)blockIdx.z * K * N, WT + (size_t)blockIdx.z * N * K,
            K, N, blockIdx.x * 64, blockIdx.y * 64, threadIdx.x, T);
}

// ---------------- slow-path kernels (proven; read raw fp32 weights) ----------------
__global__ void k_build(const int* __restrict__ ridx, int* __restrict__ seg,
                        int* __restrict__ d64, int* __restrict__ d128,
                        int* __restrict__ slot_of, int* __restrict__ pos_of) {
    build_body(ridx, seg, d64, d128, slot_of, pos_of, threadIdx.x);
}

__global__ __launch_bounds__(256) void k_gateup_s(
        const float* __restrict__ x, const float* __restrict__ w,
        const float* __restrict__ bias,
        const int* __restrict__ seg, const int* __restrict__ desc,
        const int* __restrict__ slot_of, u16* __restrict__ inter) {
    int d = desc[blockIdx.x];
    if (d < 0) return;
    int e = d >> 16, mt = d & 0xffff;
    int seg0 = seg[e], Te = seg[e + 1] - seg0, m0 = mt * 64;
    __shared__ u16 As[64 * 40];
    __shared__ int tok[64];
    int tid = threadIdx.x;
    if (tid < 64) {
        int m = m0 + tid;
        tok[tid] = (m < Te) ? (slot_of[seg0 + m] >> 1) : -1;
    }
    __syncthreads();
    int lane = tid & 63, wave = tid >> 6;
    int arow = tid >> 2, acol = (tid & 3) * 8;
    int ta = tok[arow];
    int kq = lane >> 4, ml = lane & 15;
    int nb = blockIdx.y * 128 + wave * 32;
    const float* wp = w + (size_t)e * NH * NGU;
    f32x4 zero = {0.f, 0.f, 0.f, 0.f};
    f32x4 acc[4][2];
#pragma unroll
    for (int i = 0; i < 4; ++i) { acc[i][0] = zero; acc[i][1] = zero; }
    for (int kb = 0; kb < NH; kb += 32) {
        float4 a0 = {0, 0, 0, 0}, a1 = {0, 0, 0, 0};
        if (ta >= 0) {
            const float* xp = x + (size_t)ta * NH + kb + acol;
            a0 = *(const float4*)xp; a1 = *(const float4*)(xp + 4);
        }
        s16x8 av;
        av[0] = (short)f2bf(a0.x); av[1] = (short)f2bf(a0.y);
        av[2] = (short)f2bf(a0.z); av[3] = (short)f2bf(a0.w);
        av[4] = (short)f2bf(a1.x); av[5] = (short)f2bf(a1.y);
        av[6] = (short)f2bf(a1.z); av[7] = (short)f2bf(a1.w);
        __syncthreads();
        *(s16x8*)&As[arow * 40 + acol] = av;
        __syncthreads();
        s16x8 afr[4];
#pragma unroll
        for (int msi = 0; msi < 4; ++msi)
            afr[msi] = *(const s16x8*)&As[(msi * 16 + ml) * 40 + kq * 8];
        s16x8 bfr[2];
#pragma unroll
        for (int s = 0; s < 2; ++s) {
            const float* bp = wp + (size_t)(kb + kq * 8) * NGU + nb + s * 16 + ml;
#pragma unroll
            for (int j = 0; j < 8; ++j) bfr[s][j] = (short)f2bf(bp[(size_t)j * NGU]);
        }
#pragma unroll
        for (int msi = 0; msi < 4; ++msi)
#pragma unroll
            for (int s = 0; s < 2; ++s)
                acc[msi][s] = __builtin_amdgcn_mfma_f32_16x16x32_bf16(
                    afr[msi], bfr[s], acc[msi][s], 0, 0, 0);
    }
#pragma unroll
    for (int s = 0; s < 2; ++s) {
        int n = nb + s * 16 + ml;
        float bv = bias[e * NGU + n];
#pragma unroll
        for (int msi = 0; msi < 4; ++msi) {
#pragma unroll
            for (int r = 0; r < 4; ++r) {
                float v = acc[msi][s][r] + bv;
                float pr = __shfl_xor(v, 1, 64);
                float g = (lane & 1) ? pr : v;
                float u = (lane & 1) ? v : pr;
                g = fminf(g, 7.0f);
                u = fminf(fmaxf(u, -7.0f), 7.0f);
                float glu = g / (1.0f + __expf(-1.702f * g));
                float y = (u + 1.0f) * glu;
                int mrow = m0 + msi * 16 + kq * 4 + r;
                if (!(lane & 1) && mrow < Te)
                    inter[(size_t)(seg0 + mrow) * NI + (n >> 1)] = f2bf(y);
            }
        }
    }
}

__global__ __launch_bounds__(256) void k_down_s(
        const u16* __restrict__ inter, const float* __restrict__ w,
        const float* __restrict__ bias, const float* __restrict__ rw,
        const int* __restrict__ seg, const int* __restrict__ desc,
        const int* __restrict__ slot_of, float* __restrict__ out) {
    int d = desc[blockIdx.x];
    if (d < 0) return;
    int e = d >> 16, mt = d & 0xffff;
    int seg0 = seg[e], Te = seg[e + 1] - seg0, m0 = mt * 64;
    __shared__ u16 As[64 * 40];
    int tid = threadIdx.x;
    int lane = tid & 63, wave = tid >> 6;
    int arow = tid >> 2, acol = (tid & 3) * 8;
    bool avalid = (m0 + arow) < Te;
    int kq = lane >> 4, ml = lane & 15;
    int nb = blockIdx.y * 128 + wave * 32;
    const float* wp = w + (size_t)e * NI * NH;
    f32x4 zero = {0.f, 0.f, 0.f, 0.f};
    f32x4 acc[4][2];
#pragma unroll
    for (int i = 0; i < 4; ++i) { acc[i][0] = zero; acc[i][1] = zero; }
    for (int kb = 0; kb < NI; kb += 32) {
        s16x8 av = {0, 0, 0, 0, 0, 0, 0, 0};
        if (avalid) av = *(const s16x8*)(inter + (size_t)(seg0 + m0 + arow) * NI + kb + acol);
        __syncthreads();
        *(s16x8*)&As[arow * 40 + acol] = av;
        __syncthreads();
        s16x8 afr[4];
#pragma unroll
        for (int msi = 0; msi < 4; ++msi)
            afr[msi] = *(const s16x8*)&As[(msi * 16 + ml) * 40 + kq * 8];
        s16x8 bfr[2];
#pragma unroll
        for (int s = 0; s < 2; ++s) {
            const float* bp = wp + (size_t)(kb + kq * 8) * NH + nb + s * 16 + ml;
#pragma unroll
            for (int j = 0; j < 8; ++j) bfr[s][j] = (short)f2bf(bp[(size_t)j * NH]);
        }
#pragma unroll
        for (int msi = 0; msi < 4; ++msi)
#pragma unroll
            for (int s = 0; s < 2; ++s)
                acc[msi][s] = __builtin_amdgcn_mfma_f32_16x16x32_bf16(
                    afr[msi], bfr[s], acc[msi][s], 0, 0, 0);
    }
    float bv[2];
    bv[0] = bias[e * NH + nb + ml];
    bv[1] = bias[e * NH + nb + 16 + ml];
#pragma unroll
    for (int msi = 0; msi < 4; ++msi) {
#pragma unroll
        for (int r = 0; r < 4; ++r) {
            int mrow = m0 + msi * 16 + kq * 4 + r;
            if (mrow < Te) {
                int slot = slot_of[seg0 + mrow];
                int token = slot >> 1;
                float wgt = rw[token * NE + e];
#pragma unroll
                for (int s = 0; s < 2; ++s) {
                    int n = nb + s * 16 + ml;
                    atomicAdd(&out[(size_t)token * NH + n], (acc[msi][s][r] + bv[s]) * wgt);
                }
            }
        }
    }
}

extern "C" void kernel_launch(void* const* d_in, const int* in_sizes, int n_in,
                              void* d_out, int out_size, void* d_ws, size_t ws_size,
                              hipStream_t stream) {
    const float* x   = (const float*)d_in[0];
    const int*   ri  = (const int*)d_in[1];
    const float* rw  = (const float*)d_in[2];
    const float* wgu = (const float*)d_in[3];
    const float* bgu = (const float*)d_in[4];
    const float* wd  = (const float*)d_in[5];
    const float* bd  = (const float*)d_in[6];
    float* out = (float*)d_out;

    char* ws = (char*)d_ws;
    int* seg     = (int*)(ws + WS_SEG);
    int* d64     = (int*)(ws + WS_DESC64);
    int* d128    = (int*)(ws + WS_DESC128);
    int* slot_of = (int*)(ws + WS_SLOT);
    int* pos_of  = (int*)(ws + WS_POS);
    u16* inter   = (u16*)(ws + WS_INTER);

    if (ws_size >= WS_NEED_PIGGY) {
        u16* aReg = (u16*)(ws + WS_AREG);
        u16* wReg = (u16*)(ws + WS_WREG);     // WT_gu (tiled)
        u16* wtd  = (u16*)(ws + WS_WTD);      // WT_d (tiled, disjoint)
        // launch 1: build + x->bf16 + out zero + BOTH weight transposes (tiled dest)
        hipLaunchKernelGGL(k_prep, dim3(1 + MTOK + 4096 + 2048), dim3(256), 0, stream,
                           x, ri, wgu, wd, seg, d64, d128, slot_of, pos_of,
                           aReg, wReg, wtd, out);
        // launch 2: pure gate_up GEMM (640 blocks)
        hipLaunchKernelGGL(k_gateup_f, dim3(MAXT128, NGU / 64), dim3(256), 0, stream,
                           aReg, wReg, bgu, seg, d128, slot_of, inter);
        // launch 3: down GEMM split-Kx2 (1280 blocks) + atomic scatter
        hipLaunchKernelGGL(k_down_f, dim3(MAXT128, NH / 64, 2), dim3(256), 0, stream,
                           inter, wtd, bd, rw, seg, d128, slot_of, out);
    } else if (ws_size >= WS_NEED_FAST) {
        u16* aReg = (u16*)(ws + WS_AREG);
        u16* wReg = (u16*)(ws + WS_WREG);
        hipLaunchKernelGGL(k_prep, dim3(1 + MTOK + 4096), dim3(256), 0, stream,
                           x, ri, wgu, wd, seg, d64, d128, slot_of, pos_of,
                           aReg, wReg, wReg /*unused tr_d range*/, out);
        hipLaunchKernelGGL(k_gateup_f, dim3(MAXT128, NGU / 64), dim3(256), 0, stream,
                           aReg, wReg, bgu, seg, d128, slot_of, inter);
        hipLaunchKernelGGL(k_tr, dim3(NH / 64, NI / 64, NE), dim3(256), 0, stream,
                           wd, wReg, NI, NH);
        hipLaunchKernelGGL(k_down_f, dim3(MAXT128, NH / 64, 2), dim3(256), 0, stream,
                           inter, wReg, bd, rw, seg, d128, slot_of, out);
    } else {
        hipLaunchKernelGGL(k_build, dim3(1), dim3(256), 0, stream, ri, seg, d64, d128,
                           slot_of, pos_of);
        hipMemsetAsync(out, 0, (size_t)MTOK * NH * sizeof(float), stream);
        hipLaunchKernelGGL(k_gateup_s, dim3(MAXT64, NGU / 128), dim3(256), 0, stream,
                           x, wgu, bgu, seg, d64, slot_of, inter);
        hipLaunchKernelGGL(k_down_s, dim3(MAXT64, NH / 128), dim3(256), 0, stream,
                           inter, wd, bd, rw, seg, d64, slot_of, out);
    }
}

// Round 9
// 217.060 us; speedup vs baseline: 2.8379x; 1.0100x over previous
//
#include <hip/hip_runtime.h>

#define NE 8
#define NH 1024
#define NI 1024
#define NGU 2048
#define MTOK 2048
#define TSLOT 4096

#define MAXT64 80     // slow path: 64-row tiles
#define MAXT128 40    // fast path: 128-row tiles

typedef short s16x8 __attribute__((ext_vector_type(8)));
typedef float f32x4 __attribute__((ext_vector_type(4)));
typedef unsigned short u16;

// ---- ws layout (bytes) ----
#define WS_SEG      0
#define WS_DESC64   64
#define WS_DESC128  384
#define WS_SLOT     1024          // 4096 ints -> 17408
#define WS_POS      17408         // 4096 ints -> 33792
#define WS_INTER    33792         // bf16 [4096][1024] -> +8388608 = 8422400
#define WS_AREG     8422400UL     // A bf16 [2048][1024] unsorted (4.19MB) -> 12616704
#define WS_WREG     12616704UL    // WT_gu bf16 33.55MB -> 46171136
#define WS_WTD      46171136UL    // WT_d bf16 16.78MB -> 62948352
#define WS_NEED_FAST  46171136UL
#define WS_NEED_PIGGY 62948352UL

__device__ inline u16 f2bf(float f) {
    unsigned u = __builtin_bit_cast(unsigned, f);
    u += 0x7fffu + ((u >> 16) & 1u);
    return (u16)(u >> 16);
}

__device__ inline void lds_dma16(const u16* g, u16* l) {
    __builtin_amdgcn_global_load_lds(
        (const __attribute__((address_space(1))) unsigned int*)g,
        (__attribute__((address_space(3))) unsigned int*)l, 16, 0, 0);
}

// swizzled LDS byte offset: row-stride 128B (64 bf16), 16B chunks XORed by row&7
__device__ inline int lds_off(int row, int blk) {
    return (row << 7) | (((blk ^ (row & 7)) & 7) << 4);
}

#define PIPE_FENCE asm volatile("" ::: "memory")
#define WAIT_VM6   asm volatile("s_waitcnt vmcnt(6)" ::: "memory")
#define WAIT_VM0   asm volatile("s_waitcnt vmcnt(0)" ::: "memory")

// ---- transpose tile into TILED layout: WT[e][k/64][n][64] ----
// output tile (k0,n0) = 8KB fully contiguous block at ((k0/64)*N + n0)*64
__device__ inline void tr_tile(const float* __restrict__ in, u16* __restrict__ outw,
                               int K, int N, int n0, int k0, int tid, u16 (*T)[66]) {
#pragma unroll
    for (int p = 0; p < 2; ++p) {
        int kr = p * 32 + (tid >> 4) * 2;      // even k row
        int nc = (tid & 15) * 4;
        const float* r0 = in + (size_t)(k0 + kr) * N + n0 + nc;
        float4 v0 = *(const float4*)r0;
        float4 v1 = *(const float4*)(r0 + N);
#pragma unroll
        for (int i = 0; i < 4; ++i) {
            unsigned lo = f2bf(((const float*)&v0)[i]);
            unsigned hi = f2bf(((const float*)&v1)[i]);
            *(unsigned*)&T[nc + i][kr] = lo | (hi << 16);
        }
    }
    __syncthreads();
#pragma unroll
    for (int p = 0; p < 2; ++p) {
        int idx = p * 256 + tid;
        int nr = idx >> 3, kc = (idx & 7) * 8;
        unsigned q0 = *(const unsigned*)&T[nr][kc + 0];
        unsigned q1 = *(const unsigned*)&T[nr][kc + 2];
        unsigned q2 = *(const unsigned*)&T[nr][kc + 4];
        unsigned q3 = *(const unsigned*)&T[nr][kc + 6];
        uint4 vv = {q0, q1, q2, q3};
        *(uint4*)(outw + ((size_t)(k0 >> 6) * N + n0 + nr) * 64 + kc) = vv;
    }
}

// ---- expert-sort (STABLE counting sort: ascending slot within expert) + descriptors ----
__device__ inline void build_body(const int* __restrict__ ridx, int* __restrict__ seg,
                                  int* __restrict__ d64, int* __restrict__ d128,
                                  int* __restrict__ slot_of, int* __restrict__ pos_of,
                                  int tid) {
    __shared__ int hist[256][NE];
    __shared__ int cnt[NE];
#pragma unroll
    for (int e = 0; e < NE; ++e) hist[tid][e] = 0;
    __syncthreads();
    for (int i = 0; i < 16; ++i) {
        int e = ridx[tid * 16 + i] & 7;
        hist[tid][e]++;
    }
    __syncthreads();
    if (tid < NE) {
        int run = 0;
        for (int c = 0; c < 256; ++c) { int t = hist[c][tid]; hist[c][tid] = run; run += t; }
        cnt[tid] = run;
    }
    __syncthreads();
    if (tid == 0) {
        int a = 0;
        for (int e = 0; e < NE; ++e) { seg[e] = a; a += cnt[e]; }
        seg[NE] = a;
        int nt = 0;
        for (int e = 0; e < NE; ++e)
            for (int m0 = 0; m0 < cnt[e]; m0 += 64) d64[nt++] = (e << 16) | (m0 / 64);
        for (; nt < MAXT64; ++nt) d64[nt] = -1;
        nt = 0;
        for (int e = 0; e < NE; ++e)
            for (int m0 = 0; m0 < cnt[e]; m0 += 128) d128[nt++] = (e << 16) | (m0 / 128);
        for (; nt < MAXT128; ++nt) d128[nt] = -1;
    }
    __syncthreads();
    for (int i = 0; i < 16; ++i) {
        int s = tid * 16 + i;
        int e = ridx[s] & 7;
        int p = seg[e] + hist[tid][e]++;
        slot_of[p] = s;
        pos_of[s] = p;
    }
}

// ---- shared GEMM pipeline: 128x64 tile, dbuf, counted vmcnt; B in tiled layout ----
__device__ __forceinline__ void gemm_pipe(const u16* const ap[4], const u16* const bp[2],
                                          size_t bks, char* SM, int tid, int kbeg,
                                          int nsteps, f32x4 (&acc)[4][2]) {
    u16* As0 = (u16*)SM;
    u16* As1 = (u16*)(SM + 16384);
    u16* Bs0 = (u16*)(SM + 32768);
    u16* Bs1 = (u16*)(SM + 40960);
    int lane = tid & 63, w = tid >> 6;
    int ml = lane & 15, kq = lane >> 4;
    int wm = w >> 1, wn = w & 1;

    auto stage = [&](u16* AS, u16* BS, int kb) {
#pragma unroll
        for (int c = 0; c < 4; ++c) lds_dma16(ap[c] + kb, AS + c * 2048 + w * 512);
        size_t bo = (size_t)(kb >> 6) * bks;
#pragma unroll
        for (int c = 0; c < 2; ++c) lds_dma16(bp[c] + bo, BS + c * 2048 + w * 512);
    };
    auto compute = [&](const u16* AS, const u16* BS) {
#pragma unroll
        for (int kk = 0; kk < 64; kk += 32) {
            s16x8 af[4], bf[2];
#pragma unroll
            for (int i = 0; i < 4; ++i)
                af[i] = *(const s16x8*)((const char*)AS + lds_off(wm * 64 + i * 16 + ml, (kk >> 3) + kq));
#pragma unroll
            for (int i = 0; i < 2; ++i)
                bf[i] = *(const s16x8*)((const char*)BS + lds_off(wn * 32 + i * 16 + ml, (kk >> 3) + kq));
#pragma unroll
            for (int mi = 0; mi < 4; ++mi)
#pragma unroll
                for (int ni = 0; ni < 2; ++ni)
                    acc[mi][ni] = __builtin_amdgcn_mfma_f32_16x16x32_bf16(
                        af[mi], bf[ni], acc[mi][ni], 0, 0, 0);
        }
    };

    stage(As0, Bs0, kbeg);
    for (int t = 0; t < nsteps; t += 2) {
        stage(As1, Bs1, kbeg + ((t + 1) << 6));
        WAIT_VM6;
        __builtin_amdgcn_s_barrier();
        PIPE_FENCE;
        __builtin_amdgcn_s_setprio(1);
        compute(As0, Bs0);
        __builtin_amdgcn_s_setprio(0);
        PIPE_FENCE;
        __builtin_amdgcn_s_barrier();
        if (t < nsteps - 2) {
            stage(As0, Bs0, kbeg + ((t + 2) << 6));
            WAIT_VM6;
        } else {
            WAIT_VM0;
        }
        __builtin_amdgcn_s_barrier();
        PIPE_FENCE;
        __builtin_amdgcn_s_setprio(1);
        compute(As1, Bs1);
        __builtin_amdgcn_s_setprio(0);
        PIPE_FENCE;
        __builtin_amdgcn_s_barrier();
    }
}

// ---- gate_up tile job: GEMM + swiglu epilogue ----
__device__ __forceinline__ void job_gateup(
        int d, int y, const u16* __restrict__ A, const u16* __restrict__ wt,
        const float* __restrict__ bias, const int* __restrict__ seg,
        const int* __restrict__ slot_of, u16* __restrict__ inter,
        char* SM, int tid) {
    int e = d >> 16, mt = d & 0xffff;
    int seg0 = seg[e], Te = seg[e + 1] - seg0, m0 = mt * 128;
    int lane = tid & 63, w = tid >> 6;
    int ml = lane & 15, kq = lane >> 4;
    int wm = w >> 1, wn = w & 1;
    int n0 = y * 64;
    int dr = lane >> 3, db = (lane & 7) ^ dr;
    const u16* wte = wt + (size_t)e * NGU * NH;   // tiled: [NH/64][NGU][64]

    const u16* ap[4];
#pragma unroll
    for (int c = 0; c < 4; ++c) {
        int gr = seg0 + m0 + c * 32 + w * 8 + dr;
        if (gr > TSLOT - 1) gr = TSLOT - 1;
        int tok = slot_of[gr] >> 1;
        ap[c] = A + (size_t)tok * NH + db * 8;
    }
    const u16* bp[2];
#pragma unroll
    for (int c = 0; c < 2; ++c)
        bp[c] = wte + (size_t)(n0 + c * 32 + w * 8 + dr) * 64 + db * 8;

    f32x4 zero = {0.f, 0.f, 0.f, 0.f};
    f32x4 acc[4][2];
#pragma unroll
    for (int i = 0; i < 4; ++i) { acc[i][0] = zero; acc[i][1] = zero; }

    gemm_pipe(ap, bp, (size_t)NGU * 64, SM, tid, 0, 16, acc);

#pragma unroll
    for (int ni = 0; ni < 2; ++ni) {
        int n = n0 + wn * 32 + ni * 16 + ml;
        float bv = bias[e * NGU + n];
#pragma unroll
        for (int mi = 0; mi < 4; ++mi) {
#pragma unroll
            for (int r = 0; r < 4; ++r) {
                float v = acc[mi][ni][r] + bv;
                float pr = __shfl_xor(v, 1, 64);
                float g = (lane & 1) ? pr : v;
                float u = (lane & 1) ? v : pr;
                g = fminf(g, 7.0f);
                u = fminf(fmaxf(u, -7.0f), 7.0f);
                float glu = g / (1.0f + __expf(-1.702f * g));
                float yv = (u + 1.0f) * glu;
                int mloc = wm * 64 + mi * 16 + kq * 4 + r;
                if (!(lane & 1) && (m0 + mloc) < Te)
                    inter[(size_t)(seg0 + m0 + mloc) * NI + (n >> 1)] = f2bf(yv);
            }
        }
    }
}

// ---- down tile job: split-K GEMM + weighted atomic scatter epilogue ----
__device__ __forceinline__ void job_down(
        int d, int y, int kz, const u16* __restrict__ inter, const u16* __restrict__ wt,
        const float* __restrict__ bias, const float* __restrict__ rw,
        const int* __restrict__ seg, const int* __restrict__ slot_of,
        float* __restrict__ out, char* SM, int tid) {
    int e = d >> 16, mt = d & 0xffff;
    int seg0 = seg[e], Te = seg[e + 1] - seg0, m0 = mt * 128;
    int* tokS = (int*)(SM + 49152);
    float* wgtS = (float*)(SM + 49664);

    if (tid < 128) {
        int m = m0 + tid;
        if (m < Te) {
            int token = slot_of[seg0 + m] >> 1;
            tokS[tid] = token;
            wgtS[tid] = rw[token * NE + e];
        } else {
            tokS[tid] = 0;
            wgtS[tid] = 0.0f;
        }
    }

    int lane = tid & 63, w = tid >> 6;
    int ml = lane & 15, kq = lane >> 4;
    int wm = w >> 1, wn = w & 1;
    int n0 = y * 64;
    int dr = lane >> 3, db = (lane & 7) ^ dr;
    const u16* wte = wt + (size_t)e * NH * NI;    // tiled: [NI/64][NH][64]

    const u16* ap[4];
#pragma unroll
    for (int c = 0; c < 4; ++c) {
        int gr = seg0 + m0 + c * 32 + w * 8 + dr;
        if (gr > TSLOT - 1) gr = TSLOT - 1;
        ap[c] = inter + (size_t)gr * NI + db * 8;
    }
    const u16* bp[2];
#pragma unroll
    for (int c = 0; c < 2; ++c)
        bp[c] = wte + (size_t)(n0 + c * 32 + w * 8 + dr) * 64 + db * 8;

    f32x4 zero = {0.f, 0.f, 0.f, 0.f};
    f32x4 acc[4][2];
#pragma unroll
    for (int i = 0; i < 4; ++i) { acc[i][0] = zero; acc[i][1] = zero; }

    gemm_pipe(ap, bp, (size_t)NH * 64, SM, tid, kz * (NI / 2), 8, acc);

    float bv[2];
#pragma unroll
    for (int ni = 0; ni < 2; ++ni)
        bv[ni] = kz ? 0.0f : bias[e * NH + n0 + wn * 32 + ni * 16 + ml];

#pragma unroll
    for (int mi = 0; mi < 4; ++mi) {
#pragma unroll
        for (int r = 0; r < 4; ++r) {
            int mloc = wm * 64 + mi * 16 + kq * 4 + r;
            if ((m0 + mloc) < Te) {
                int token = tokS[mloc];
                float wgt = wgtS[mloc];
#pragma unroll
                for (int ni = 0; ni < 2; ++ni) {
                    int n = n0 + wn * 32 + ni * 16 + ml;
                    atomicAdd(&out[(size_t)token * NH + n], (acc[mi][ni][r] + bv[ni]) * wgt);
                }
            }
        }
    }
}

// ---------------- fused prep: build(1) + convert/zero(2048) + tr_gu(4096) + tr_d(2048) ----------------
__global__ __launch_bounds__(256) void k_prep(
        const float* __restrict__ x, const int* __restrict__ ridx,
        const float* __restrict__ wgu, const float* __restrict__ wd,
        int* __restrict__ seg, int* __restrict__ d64, int* __restrict__ d128,
        int* __restrict__ slot_of, int* __restrict__ pos_of,
        u16* __restrict__ A, u16* __restrict__ wt_gu, u16* __restrict__ wt_d,
        float* __restrict__ out) {
    __shared__ u16 T[64][66];
    int b = blockIdx.x;
    int tid = threadIdx.x;
    if (b == 0) {
        build_body(ridx, seg, d64, d128, slot_of, pos_of, tid);
    } else if (b <= MTOK) {
        int t = b - 1;
        float4 v = ((const float4*)(x + (size_t)t * NH))[tid];
        ushort4 o;
        o.x = f2bf(v.x); o.y = f2bf(v.y); o.z = f2bf(v.z); o.w = f2bf(v.w);
        ((ushort4*)(A + (size_t)t * NH))[tid] = o;
        float4 z = {0.f, 0.f, 0.f, 0.f};
        ((float4*)(out + (size_t)t * NH))[tid] = z;
    } else if (b <= MTOK + 4096) {
        int id = b - (MTOK + 1);                 // 0..4095
        int e = id >> 9, rem = id & 511;
        int kblk = rem >> 5, nblk = rem & 31;    // K=NH: 16 kblks, N=NGU: 32 nblks
        tr_tile(wgu + (size_t)e * NH * NGU, wt_gu + (size_t)e * NGU * NH,
                NH, NGU, nblk * 64, kblk * 64, tid, T);
    } else {
        int id = b - (MTOK + 4097);              // 0..2047
        int e = id >> 8, rem = id & 255;
        int kblk = rem >> 4, nblk = rem & 15;    // K=NI:16, N=NH:16
        tr_tile(wd + (size_t)e * NI * NH, wt_d + (size_t)e * NH * NI,
                NI, NH, nblk * 64, kblk * 64, tid, T);
    }
}

// ---------------- fast gate_up: flat grid 1280, XCD-swizzled (x-range per XCD) ----------------
__global__ __launch_bounds__(256) void k_gateup_f(
        const u16* __restrict__ A, const u16* __restrict__ wt,
        const float* __restrict__ bias,
        const int* __restrict__ seg, const int* __restrict__ desc,
        const int* __restrict__ slot_of, u16* __restrict__ inter) {
    __shared__ __align__(16) char SM[50176];
    // bid%8 == XCD (dispatch round-robin); 40 % 8 == 0 so s%8 == bid%8.
    // XCD a gets x in [5a, 5a+5): its A working set (1.25MB) stays L2-hot across all y.
    int bid = blockIdx.x;
    int s = bid % MAXT128;
    int x = (s % 8) * 5 + s / 8;
    int y = bid / MAXT128;
    int d = desc[x];
    if (d < 0) return;
    job_gateup(d, y, A, wt, bias, seg, slot_of, inter, SM, threadIdx.x);
}

// ---------------- fast down: flat grid 1280, XCD-swizzled, split-Kx2 ----------------
__global__ __launch_bounds__(256) void k_down_f(
        const u16* __restrict__ inter, const u16* __restrict__ wt,
        const float* __restrict__ bias, const float* __restrict__ rw,
        const int* __restrict__ seg, const int* __restrict__ desc,
        const int* __restrict__ slot_of, float* __restrict__ out) {
    __shared__ __align__(16) char SM[50176];
    int bid = blockIdx.x;
    int s = bid % MAXT128;
    int x = (s % 8) * 5 + s / 8;
    int rest = bid / MAXT128;          // 0..31
    int y = rest & 15, kz = rest >> 4;
    int d = desc[x];
    if (d < 0) return;
    job_down(d, y, kz, inter, wt, bias, rw, seg, slot_of, out, SM, threadIdx.x);
}

// ---------------- fallback standalone transpose ----------------
__global__ __launch_bounds__(256) void k_tr(const float* __restrict__ W,
                                            u16* __restrict__ WT, int K, int N) {
    __shared__ u16 T[64][66];
    tr_tile(W + (size_t)blockIdx.z * K * N, WT + (size_t)blockIdx.z * N * K,
            K, N, blockIdx.x * 64, blockIdx.y * 64, threadIdx.x, T);
}

// ---------------- slow-path kernels (proven; read raw fp32 weights) ----------------
__global__ void k_build(const int* __restrict__ ridx, int* __restrict__ seg,
                        int* __restrict__ d64, int* __restrict__ d128,
                        int* __restrict__ slot_of, int* __restrict__ pos_of) {
    build_body(ridx, seg, d64, d128, slot_of, pos_of, threadIdx.x);
}

__global__ __launch_bounds__(256) void k_gateup_s(
        const float* __restrict__ x, const float* __restrict__ w,
        const float* __restrict__ bias,
        const int* __restrict__ seg, const int* __restrict__ desc,
        const int* __restrict__ slot_of, u16* __restrict__ inter) {
    int d = desc[blockIdx.x];
    if (d < 0) return;
    int e = d >> 16, mt = d & 0xffff;
    int seg0 = seg[e], Te = seg[e + 1] - seg0, m0 = mt * 64;
    __shared__ u16 As[64 * 40];
    __shared__ int tok[64];
    int tid = threadIdx.x;
    if (tid < 64) {
        int m = m0 + tid;
        tok[tid] = (m < Te) ? (slot_of[seg0 + m] >> 1) : -1;
    }
    __syncthreads();
    int lane = tid & 63, wave = tid >> 6;
    int arow = tid >> 2, acol = (tid & 3) * 8;
    int ta = tok[arow];
    int kq = lane >> 4, ml = lane & 15;
    int nb = blockIdx.y * 128 + wave * 32;
    const float* wp = w + (size_t)e * NH * NGU;
    f32x4 zero = {0.f, 0.f, 0.f, 0.f};
    f32x4 acc[4][2];
#pragma unroll
    for (int i = 0; i < 4; ++i) { acc[i][0] = zero; acc[i][1] = zero; }
    for (int kb = 0; kb < NH; kb += 32) {
        float4 a0 = {0, 0, 0, 0}, a1 = {0, 0, 0, 0};
        if (ta >= 0) {
            const float* xp = x + (size_t)ta * NH + kb + acol;
            a0 = *(const float4*)xp; a1 = *(const float4*)(xp + 4);
        }
        s16x8 av;
        av[0] = (short)f2bf(a0.x); av[1] = (short)f2bf(a0.y);
        av[2] = (short)f2bf(a0.z); av[3] = (short)f2bf(a0.w);
        av[4] = (short)f2bf(a1.x); av[5] = (short)f2bf(a1.y);
        av[6] = (short)f2bf(a1.z); av[7] = (short)f2bf(a1.w);
        __syncthreads();
        *(s16x8*)&As[arow * 40 + acol] = av;
        __syncthreads();
        s16x8 afr[4];
#pragma unroll
        for (int msi = 0; msi < 4; ++msi)
            afr[msi] = *(const s16x8*)&As[(msi * 16 + ml) * 40 + kq * 8];
        s16x8 bfr[2];
#pragma unroll
        for (int s = 0; s < 2; ++s) {
            const float* bp = wp + (size_t)(kb + kq * 8) * NGU + nb + s * 16 + ml;
#pragma unroll
            for (int j = 0; j < 8; ++j) bfr[s][j] = (short)f2bf(bp[(size_t)j * NGU]);
        }
#pragma unroll
        for (int msi = 0; msi < 4; ++msi)
#pragma unroll
            for (int s = 0; s < 2; ++s)
                acc[msi][s] = __builtin_amdgcn_mfma_f32_16x16x32_bf16(
                    afr[msi], bfr[s], acc[msi][s], 0, 0, 0);
    }
#pragma unroll
    for (int s = 0; s < 2; ++s) {
        int n = nb + s * 16 + ml;
        float bv = bias[e * NGU + n];
#pragma unroll
        for (int msi = 0; msi < 4; ++msi) {
#pragma unroll
            for (int r = 0; r < 4; ++r) {
                float v = acc[msi][s][r] + bv;
                float pr = __shfl_xor(v, 1, 64);
                float g = (lane & 1) ? pr : v;
                float u = (lane & 1) ? v : pr;
                g = fminf(g, 7.0f);
                u = fminf(fmaxf(u, -7.0f), 7.0f);
                float glu = g / (1.0f + __expf(-1.702f * g));
                float y = (u + 1.0f) * glu;
                int mrow = m0 + msi * 16 + kq * 4 + r;
                if (!(lane & 1) && mrow < Te)
                    inter[(size_t)(seg0 + mrow) * NI + (n >> 1)] = f2bf(y);
            }
        }
    }
}

__global__ __launch_bounds__(256) void k_down_s(
        const u16* __restrict__ inter, const float* __restrict__ w,
        const float* __restrict__ bias, const float* __restrict__ rw,
        const int* __restrict__ seg, const int* __restrict__ desc,
        const int* __restrict__ slot_of, float* __restrict__ out) {
    int d = desc[blockIdx.x];
    if (d < 0) return;
    int e = d >> 16, mt = d & 0xffff;
    int seg0 = seg[e], Te = seg[e + 1] - seg0, m0 = mt * 64;
    __shared__ u16 As[64 * 40];
    int tid = threadIdx.x;
    int lane = tid & 63, wave = tid >> 6;
    int arow = tid >> 2, acol = (tid & 3) * 8;
    bool avalid = (m0 + arow) < Te;
    int kq = lane >> 4, ml = lane & 15;
    int nb = blockIdx.y * 128 + wave * 32;
    const float* wp = w + (size_t)e * NI * NH;
    f32x4 zero = {0.f, 0.f, 0.f, 0.f};
    f32x4 acc[4][2];
#pragma unroll
    for (int i = 0; i < 4; ++i) { acc[i][0] = zero; acc[i][1] = zero; }
    for (int kb = 0; kb < NI; kb += 32) {
        s16x8 av = {0, 0, 0, 0, 0, 0, 0, 0};
        if (avalid) av = *(const s16x8*)(inter + (size_t)(seg0 + m0 + arow) * NI + kb + acol);
        __syncthreads();
        *(s16x8*)&As[arow * 40 + acol] = av;
        __syncthreads();
        s16x8 afr[4];
#pragma unroll
        for (int msi = 0; msi < 4; ++msi)
            afr[msi] = *(const s16x8*)&As[(msi * 16 + ml) * 40 + kq * 8];
        s16x8 bfr[2];
#pragma unroll
        for (int s = 0; s < 2; ++s) {
            const float* bp = wp + (size_t)(kb + kq * 8) * NH + nb + s * 16 + ml;
#pragma unroll
            for (int j = 0; j < 8; ++j) bfr[s][j] = (short)f2bf(bp[(size_t)j * NH]);
        }
#pragma unroll
        for (int msi = 0; msi < 4; ++msi)
#pragma unroll
            for (int s = 0; s < 2; ++s)
                acc[msi][s] = __builtin_amdgcn_mfma_f32_16x16x32_bf16(
                    afr[msi], bfr[s], acc[msi][s], 0, 0, 0);
    }
    float bv[2];
    bv[0] = bias[e * NH + nb + ml];
    bv[1] = bias[e * NH + nb + 16 + ml];
#pragma unroll
    for (int msi = 0; msi < 4; ++msi) {
#pragma unroll
        for (int r = 0; r < 4; ++r) {
            int mrow = m0 + msi * 16 + kq * 4 + r;
            if (mrow < Te) {
                int slot = slot_of[seg0 + mrow];
                int token = slot >> 1;
                float wgt = rw[token * NE + e];
#pragma unroll
                for (int s = 0; s < 2; ++s) {
                    int n = nb + s * 16 + ml;
                    atomicAdd(&out[(size_t)token * NH + n], (acc[msi][s][r] + bv[s]) * wgt);
                }
            }
        }
    }
}

extern "C" void kernel_launch(void* const* d_in, const int* in_sizes, int n_in,
                              void* d_out, int out_size, void* d_ws, size_t ws_size,
                              hipStream_t stream) {
    const float* x   = (const float*)d_in[0];
    const int*   ri  = (const int*)d_in[1];
    const float* rw  = (const float*)d_in[2];
    const float* wgu = (const float*)d_in[3];
    const float* bgu = (const float*)d_in[4];
    const float* wd  = (const float*)d_in[5];
    const float* bd  = (const float*)d_in[6];
    float* out = (float*)d_out;

    char* ws = (char*)d_ws;
    int* seg     = (int*)(ws + WS_SEG);
    int* d64     = (int*)(ws + WS_DESC64);
    int* d128    = (int*)(ws + WS_DESC128);
    int* slot_of = (int*)(ws + WS_SLOT);
    int* pos_of  = (int*)(ws + WS_POS);
    u16* inter   = (u16*)(ws + WS_INTER);

    if (ws_size >= WS_NEED_PIGGY) {
        u16* aReg = (u16*)(ws + WS_AREG);
        u16* wReg = (u16*)(ws + WS_WREG);     // WT_gu (tiled)
        u16* wtd  = (u16*)(ws + WS_WTD);      // WT_d (tiled, disjoint)
        // launch 1: build + x->bf16 + out zero + BOTH weight transposes (tiled dest)
        hipLaunchKernelGGL(k_prep, dim3(1 + MTOK + 4096 + 2048), dim3(256), 0, stream,
                           x, ri, wgu, wd, seg, d64, d128, slot_of, pos_of,
                           aReg, wReg, wtd, out);
        // launch 2: gate_up GEMM, flat 1280 blocks, XCD-swizzled
        hipLaunchKernelGGL(k_gateup_f, dim3(MAXT128 * (NGU / 64)), dim3(256), 0, stream,
                           aReg, wReg, bgu, seg, d128, slot_of, inter);
        // launch 3: down GEMM split-Kx2, flat 1280 blocks, XCD-swizzled
        hipLaunchKernelGGL(k_down_f, dim3(MAXT128 * (NH / 64) * 2), dim3(256), 0, stream,
                           inter, wtd, bd, rw, seg, d128, slot_of, out);
    } else if (ws_size >= WS_NEED_FAST) {
        u16* aReg = (u16*)(ws + WS_AREG);
        u16* wReg = (u16*)(ws + WS_WREG);
        hipLaunchKernelGGL(k_prep, dim3(1 + MTOK + 4096), dim3(256), 0, stream,
                           x, ri, wgu, wd, seg, d64, d128, slot_of, pos_of,
                           aReg, wReg, wReg /*unused tr_d range*/, out);
        hipLaunchKernelGGL(k_gateup_f, dim3(MAXT128 * (NGU / 64)), dim3(256), 0, stream,
                           aReg, wReg, bgu, seg, d128, slot_of, inter);
        hipLaunchKernelGGL(k_tr, dim3(NH / 64, NI / 64, NE), dim3(256), 0, stream,
                           wd, wReg, NI, NH);
        hipLaunchKernelGGL(k_down_f, dim3(MAXT128 * (NH / 64) * 2), dim3(256), 0, stream,
                           inter, wReg, bd, rw, seg, d128, slot_of, out);
    } else {
        hipLaunchKernelGGL(k_build, dim3(1), dim3(256), 0, stream, ri, seg, d64, d128,
                           slot_of, pos_of);
        hipMemsetAsync(out, 0, (size_t)MTOK * NH * sizeof(float), stream);
        hipLaunchKernelGGL(k_gateup_s, dim3(MAXT64, NGU / 128), dim3(256), 0, stream,
                           x, wgu, bgu, seg, d64, slot_of, inter);
        hipLaunchKernelGGL(k_down_s, dim3(MAXT64, NH / 128), dim3(256), 0, stream,
                           inter, wd, bd, rw, seg, d64, slot_of, out);
    }
}